// Round 3
// baseline (802.590 us; speedup 1.0000x reference)
//
#include <hip/hip_runtime.h>
#include <hip/hip_fp16.h>

#define N_NODES 100000
#define EMB_DIM 64
#define N_EDGES 3200000
#define N_LAYERS 3

#define SCAN_BLOCK 512
#define N_SCAN_BLOCKS ((N_NODES + SCAN_BLOCK - 1) / SCAN_BLOCK)   // 196

#define BUCKET_ROWS 25
#define NB_BUCKETS (N_NODES / BUCKET_ROWS)   // 4000, exact

// d_out layout: mean [N_NODES*64] first, then stacked [N_NODES*4*64]
// stacked[n][l][d] at n*256 + l*64 + d

__device__ __forceinline__ unsigned short f32_to_bf16_rtn(float f) {
    unsigned u = __float_as_uint(f);
    unsigned r = u + 0x7FFFu + ((u >> 16) & 1u);
    return (unsigned short)(r >> 16);
}
__device__ __forceinline__ float bf16_to_f32(unsigned short h) {
    return __uint_as_float(((unsigned)h) << 16);
}

// ---------- CSR build ----------

__global__ void count_rows(const int* __restrict__ rows, int* __restrict__ counts) {
    int e = blockIdx.x * blockDim.x + threadIdx.x;
    if (e >= N_EDGES) return;
    atomicAdd(&counts[rows[e]], 1);
}

__global__ void __launch_bounds__(SCAN_BLOCK) scan_phase1(const int* __restrict__ counts,
                                                          int* __restrict__ blockSums) {
    __shared__ int sm[SCAN_BLOCK];
    int idx = blockIdx.x * SCAN_BLOCK + threadIdx.x;
    int v = (idx < N_NODES) ? counts[idx] : 0;
    sm[threadIdx.x] = v;
    __syncthreads();
    for (int off = SCAN_BLOCK / 2; off > 0; off >>= 1) {
        if (threadIdx.x < off) sm[threadIdx.x] += sm[threadIdx.x + off];
        __syncthreads();
    }
    if (threadIdx.x == 0) blockSums[blockIdx.x] = sm[0];
}

__global__ void __launch_bounds__(256) scan_phase2(const int* __restrict__ blockSums,
                                                   int* __restrict__ blockOffs,
                                                   int* __restrict__ row_ptr) {
    __shared__ int sm[256];
    int t = threadIdx.x;
    int v = (t < N_SCAN_BLOCKS) ? blockSums[t] : 0;
    sm[t] = v;
    __syncthreads();
    for (int off = 1; off < 256; off <<= 1) {
        int u = (t >= off) ? sm[t - off] : 0;
        __syncthreads();
        sm[t] += u;
        __syncthreads();
    }
    if (t < N_SCAN_BLOCKS) blockOffs[t] = (t == 0) ? 0 : sm[t - 1];
    if (t == 255) row_ptr[N_NODES] = sm[255];
}

__global__ void __launch_bounds__(SCAN_BLOCK) scan_phase3(const int* __restrict__ counts,
                                                          const int* __restrict__ blockOffs,
                                                          int* __restrict__ row_ptr) {
    __shared__ int sm[SCAN_BLOCK];
    int idx = blockIdx.x * SCAN_BLOCK + threadIdx.x;
    int t = threadIdx.x;
    int v = (idx < N_NODES) ? counts[idx] : 0;
    sm[t] = v;
    __syncthreads();
    for (int off = 1; off < SCAN_BLOCK; off <<= 1) {
        int u = (t >= off) ? sm[t - off] : 0;
        __syncthreads();
        sm[t] += u;
        __syncthreads();
    }
    if (idx < N_NODES) row_ptr[idx] = blockOffs[blockIdx.x] + sm[t] - v;
}

// ---------- two-phase bucketed edge scatter (kills write amplification) ----------
// Phase A: append (row, packed) 8B records into 4000 bucket regions
// (bucket base = row_ptr[b*25], exact capacity). Appends are temporally dense
// per bucket tail -> mostly full-line writes.
// Phase B: one WG per bucket; read records coalesced, resolve per-row slots in
// LDS, write packed 4B words into the bucket's contiguous s_edges window
// (~6 KB, one XCD) -> every line written fully, once.
// Packed edge: col (17 bits) << 15 | fp16(val) low 15 bits (val>=0 so sign=0).

__global__ void build_phaseA(const int* __restrict__ rows, const int* __restrict__ cols,
                             const float* __restrict__ vals,
                             const int* __restrict__ row_ptr,
                             int* __restrict__ bucketFill,
                             uint2* __restrict__ records) {
    int e = blockIdx.x * blockDim.x + threadIdx.x;
    if (e >= N_EDGES) return;
    int r = rows[e];
    int b = r / BUCKET_ROWS;                      // constant div -> magic multiply
    int base = row_ptr[b * BUCKET_ROWS];
    int pos = base + atomicAdd(&bucketFill[b], 1);
    unsigned hb = __half_as_ushort(__float2half(vals[e]));
    uint2 rec;
    rec.x = (unsigned)r;
    rec.y = (((unsigned)cols[e]) << 15) | (hb & 0x7FFFu);
    records[pos] = rec;
}

__global__ void __launch_bounds__(256) build_phaseB(const int* __restrict__ row_ptr,
                                                    const uint2* __restrict__ records,
                                                    unsigned* __restrict__ s_edges) {
    __shared__ int lfill[BUCKET_ROWS];
    int b = blockIdx.x;
    int r0 = b * BUCKET_ROWS;
    int beg = row_ptr[r0];
    int end = row_ptr[r0 + BUCKET_ROWS];
    for (int t = threadIdx.x; t < BUCKET_ROWS; t += blockDim.x) lfill[t] = 0;
    __syncthreads();
    for (int i = beg + threadIdx.x; i < end; i += blockDim.x) {
        uint2 rec = records[i];
        int r = (int)rec.x;
        int lp = atomicAdd(&lfill[r - r0], 1);
        s_edges[row_ptr[r] + lp] = rec.y;
    }
}

// Single-phase fallback scatter (f32 path keeps using row-granular atomics).
__global__ void scatter_edges_packed(const int* __restrict__ rows, const int* __restrict__ cols,
                                     const float* __restrict__ vals,
                                     const int* __restrict__ row_ptr, int* __restrict__ fill,
                                     unsigned* __restrict__ s_edges) {
    int e = blockIdx.x * blockDim.x + threadIdx.x;
    if (e >= N_EDGES) return;
    int r = rows[e];
    int pos = row_ptr[r] + atomicAdd(&fill[r], 1);
    unsigned hb = __half_as_ushort(__float2half(vals[e]));
    s_edges[pos] = (((unsigned)cols[e]) << 15) | (hb & 0x7FFFu);
}

// ---------- emb -> bf16 mirror ----------
__global__ void emb_to_bf16(const float* __restrict__ emb, ushort4* __restrict__ mirror) {
    int t = blockIdx.x * blockDim.x + threadIdx.x;   // [0, N_NODES*16)
    if (t >= N_NODES * 16) return;
    float4 v = ((const float4*)emb)[t];
    ushort4 o;
    o.x = f32_to_bf16_rtn(v.x); o.y = f32_to_bf16_rtn(v.y);
    o.z = f32_to_bf16_rtn(v.z); o.w = f32_to_bf16_rtn(v.w);
    mirror[t] = o;
}

// ---------- SpMM gather core, bf16 source: one wave per destination node ----------
// 4 groups x 16 lanes; lane j of a group owns bf16x4 chunk j of the 64-dim row.
// Edge words staged via ONE coalesced per-lane load, distributed with __shfl.
// Control flow is wave-uniform (shfl from inactive lanes is undefined on CDNA).

__device__ __forceinline__ void gacc(float4& acc, unsigned p, int j,
                                     const unsigned short* __restrict__ srcMirror) {
    float v = __half2float(__ushort_as_half((unsigned short)(p & 0x7FFFu)));
    ushort4 m = *(const ushort4*)(srcMirror + (size_t)(p >> 15) * 64 + j * 4);
    acc.x += v * bf16_to_f32(m.x);
    acc.y += v * bf16_to_f32(m.y);
    acc.z += v * bf16_to_f32(m.z);
    acc.w += v * bf16_to_f32(m.w);
}

__device__ __forceinline__ float4 spmm_row_core(int beg, int end, int g, int j, int lane,
                                                const unsigned* __restrict__ s_edges,
                                                const unsigned short* __restrict__ srcMirror) {
    int deg = end - beg;                  // wave-uniform
    unsigned ew = (lane < deg) ? s_edges[beg + lane] : 0u;
    float4 acc = make_float4(0.f, 0.f, 0.f, 0.f);
    int nfull = deg < 64 ? deg : 64;      // wave-uniform
    for (int kb = 0; kb < nfull; kb += 16) {
        int k0 = kb + g, k1 = kb + g + 4, k2 = kb + g + 8, k3 = kb + g + 12;
        unsigned p0 = __shfl(ew, k0);
        unsigned p1 = __shfl(ew, k1);
        unsigned p2 = __shfl(ew, k2);
        unsigned p3 = __shfl(ew, k3);
        if (k0 < nfull) gacc(acc, p0, j, srcMirror);
        if (k1 < nfull) gacc(acc, p1, j, srcMirror);
        if (k2 < nfull) gacc(acc, p2, j, srcMirror);
        if (k3 < nfull) gacc(acc, p3, j, srcMirror);
    }
    for (int e = beg + 64 + g; e < end; e += 4) {
        unsigned p = s_edges[e];
        gacc(acc, p, j, srcMirror);
    }
    acc.x += __shfl_xor(acc.x, 16); acc.y += __shfl_xor(acc.y, 16);
    acc.z += __shfl_xor(acc.z, 16); acc.w += __shfl_xor(acc.w, 16);
    acc.x += __shfl_xor(acc.x, 32); acc.y += __shfl_xor(acc.y, 32);
    acc.z += __shfl_xor(acc.z, 32); acc.w += __shfl_xor(acc.w, 32);
    return acc;
}

__global__ void __launch_bounds__(256) spmm_gather_bf16_mid(const int* __restrict__ row_ptr,
                                                            const unsigned* __restrict__ s_edges,
                                                            const unsigned short* __restrict__ srcMirror,
                                                            float* __restrict__ dstStacked,
                                                            unsigned short* __restrict__ dstMirror) {
    int wave = (blockIdx.x * blockDim.x + threadIdx.x) >> 6;
    if (wave >= N_NODES) return;
    int lane = threadIdx.x & 63;
    int g = lane >> 4, j = lane & 15;
    float4 acc = spmm_row_core(row_ptr[wave], row_ptr[wave + 1], g, j, lane, s_edges, srcMirror);
    if (lane < 16) {
        *(float4*)(dstStacked + (size_t)wave * 256 + j * 4) = acc;
        ushort4 o;
        o.x = f32_to_bf16_rtn(acc.x); o.y = f32_to_bf16_rtn(acc.y);
        o.z = f32_to_bf16_rtn(acc.z); o.w = f32_to_bf16_rtn(acc.w);
        *(ushort4*)(dstMirror + (size_t)wave * 64 + j * 4) = o;
    }
}

// Last layer: fuse the 4-layer mean + layer-0 copy into the same dispatch.
__global__ void __launch_bounds__(256) spmm_gather_bf16_last(const int* __restrict__ row_ptr,
                                                             const unsigned* __restrict__ s_edges,
                                                             const unsigned short* __restrict__ srcMirror,
                                                             const float* __restrict__ emb,
                                                             float* __restrict__ stacked,
                                                             float* __restrict__ meanOut) {
    int wave = (blockIdx.x * blockDim.x + threadIdx.x) >> 6;
    if (wave >= N_NODES) return;
    int lane = threadIdx.x & 63;
    int g = lane >> 4, j = lane & 15;
    float4 acc = spmm_row_core(row_ptr[wave], row_ptr[wave + 1], g, j, lane, s_edges, srcMirror);
    if (lane < 16) {
        float4* base = (float4*)stacked + (size_t)wave * 64;
        float4 a = ((const float4*)emb)[wave * 16 + j];
        float4 b = base[16 + j];
        float4 c = base[32 + j];
        base[j] = a;          // layer 0
        base[48 + j] = acc;   // layer 3
        float4 s;
        s.x = 0.25f * (a.x + b.x + c.x + acc.x);
        s.y = 0.25f * (a.y + b.y + c.y + acc.y);
        s.z = 0.25f * (a.z + b.z + c.z + acc.z);
        s.w = 0.25f * (a.w + b.w + c.w + acc.w);
        ((float4*)meanOut)[wave * 16 + j] = s;
    }
}

// ---------- mean over 4 layers (f32 fallback path) ----------
__global__ void mean_layers(const float* __restrict__ emb,
                            float* __restrict__ stacked,
                            float* __restrict__ meanOut) {
    int t = blockIdx.x * blockDim.x + threadIdx.x;   // [0, N_NODES*16)
    if (t >= N_NODES * 16) return;
    int n = t >> 4;
    int j = t & 15;
    float4* base = (float4*)stacked + (size_t)n * 64;
    float4 a = ((const float4*)emb)[t];
    float4 b = base[16 + j];
    float4 c = base[32 + j];
    float4 d = base[48 + j];
    base[j] = a;
    float4 s;
    s.x = 0.25f * (a.x + b.x + c.x + d.x);
    s.y = 0.25f * (a.y + b.y + c.y + d.y);
    s.z = 0.25f * (a.z + b.z + c.z + d.z);
    s.w = 0.25f * (a.w + b.w + c.w + d.w);
    ((float4*)meanOut)[t] = s;
}

// ---------- mid fallback: fp32 CSR gather ----------

__global__ void scatter_edges_int2(const int* __restrict__ rows, const int* __restrict__ cols,
                                   const float* __restrict__ vals,
                                   const int* __restrict__ row_ptr, int* __restrict__ fill,
                                   int2* __restrict__ s_colval) {
    int e = blockIdx.x * blockDim.x + threadIdx.x;
    if (e >= N_EDGES) return;
    int r = rows[e];
    int pos = row_ptr[r] + atomicAdd(&fill[r], 1);
    int2 p; p.x = cols[e]; p.y = __float_as_int(vals[e]);
    s_colval[pos] = p;
}

__global__ void __launch_bounds__(256) spmm_gather_f32(const int* __restrict__ row_ptr,
                                                       const int2* __restrict__ s_colval,
                                                       const float* __restrict__ src, int srcStride,
                                                       float* __restrict__ dst) {
    int wave = (blockIdx.x * blockDim.x + threadIdx.x) >> 6;
    if (wave >= N_NODES) return;
    int lane = threadIdx.x & 63;
    int g = lane >> 4, j = lane & 15;
    int beg = row_ptr[wave], end = row_ptr[wave + 1];
    float4 acc = make_float4(0.f, 0.f, 0.f, 0.f);
    int e = beg + g;
    for (; e + 4 < end; e += 8) {
        int2 p0 = s_colval[e], p1 = s_colval[e + 4];
        float v0 = __int_as_float(p0.y), v1 = __int_as_float(p1.y);
        float4 m0 = *(const float4*)(src + (size_t)p0.x * srcStride + j * 4);
        float4 m1 = *(const float4*)(src + (size_t)p1.x * srcStride + j * 4);
        acc.x += v0 * m0.x + v1 * m1.x; acc.y += v0 * m0.y + v1 * m1.y;
        acc.z += v0 * m0.z + v1 * m1.z; acc.w += v0 * m0.w + v1 * m1.w;
    }
    for (; e < end; e += 4) {
        int2 p = s_colval[e];
        float v = __int_as_float(p.y);
        float4 m = *(const float4*)(src + (size_t)p.x * srcStride + j * 4);
        acc.x += v * m.x; acc.y += v * m.y; acc.z += v * m.z; acc.w += v * m.w;
    }
    acc.x += __shfl_xor(acc.x, 16); acc.y += __shfl_xor(acc.y, 16);
    acc.z += __shfl_xor(acc.z, 16); acc.w += __shfl_xor(acc.w, 16);
    acc.x += __shfl_xor(acc.x, 32); acc.y += __shfl_xor(acc.y, 32);
    acc.z += __shfl_xor(acc.z, 32); acc.w += __shfl_xor(acc.w, 32);
    if (lane < 16)
        *(float4*)(dst + (size_t)wave * 256 + j * 4) = acc;
}

// ---------- last fallback: atomic scatter ----------

__global__ void init_stacked_full(const float* __restrict__ emb, float* __restrict__ stacked) {
    int t = blockIdx.x * blockDim.x + threadIdx.x;
    if (t >= N_NODES * 64) return;
    int n = t >> 6, j = t & 63;
    float4 v = (j < 16) ? ((const float4*)emb)[n * 16 + j] : make_float4(0.f, 0.f, 0.f, 0.f);
    ((float4*)stacked)[n * 64 + j] = v;
}

__global__ void spmm_atomic(const int* __restrict__ rows, const int* __restrict__ cols,
                            const float* __restrict__ vals, float* __restrict__ stacked,
                            int lprev) {
    int t = blockIdx.x * blockDim.x + threadIdx.x;
    int e = t >> 4, j = t & 15;
    if (e >= N_EDGES) return;
    int r = rows[e], c = cols[e];
    float v = vals[e];
    const float4* src = (const float4*)(stacked + (size_t)c * 256 + lprev * 64);
    float4 m = src[j];
    float* dst = stacked + (size_t)r * 256 + (lprev + 1) * 64 + j * 4;
    atomicAdd(dst + 0, v * m.x); atomicAdd(dst + 1, v * m.y);
    atomicAdd(dst + 2, v * m.z); atomicAdd(dst + 3, v * m.w);
}

__global__ void mean_layers_plain(const float* __restrict__ stacked, float* __restrict__ meanOut) {
    int t = blockIdx.x * blockDim.x + threadIdx.x;
    if (t >= N_NODES * 16) return;
    int n = t >> 4, j = t & 15;
    const float4* base = (const float4*)(stacked + (size_t)n * 256);
    float4 a = base[j], b = base[16 + j], c = base[32 + j], d = base[48 + j];
    float4 s;
    s.x = 0.25f * (a.x + b.x + c.x + d.x);
    s.y = 0.25f * (a.y + b.y + c.y + d.y);
    s.z = 0.25f * (a.z + b.z + c.z + d.z);
    s.w = 0.25f * (a.w + b.w + c.w + d.w);
    ((float4*)meanOut)[t] = s;
}

extern "C" void kernel_launch(void* const* d_in, const int* in_sizes, int n_in,
                              void* d_out, int out_size, void* d_ws, size_t ws_size,
                              hipStream_t stream) {
    const float* emb  = (const float*)d_in[0];
    const int*   rows = (const int*)d_in[1];
    const int*   cols = (const int*)d_in[2];
    const float* vals = (const float*)d_in[3];

    float* meanOut = (float*)d_out;
    float* stacked = (float*)d_out + (size_t)N_NODES * EMB_DIM;

    const size_t headInts = (size_t)(N_NODES * 2 + 1 + 2 * N_SCAN_BLOCKS);
    size_t need_bf16 = headInts * sizeof(int) + 64
                     + (size_t)N_EDGES * sizeof(unsigned)
                     + 2 * (size_t)N_NODES * EMB_DIM * sizeof(unsigned short);
    size_t need_f32  = headInts * sizeof(int) + 64 + (size_t)N_EDGES * sizeof(int2);

    if (ws_size >= need_bf16) {
        char* w = (char*)d_ws;
        int* counts    = (int*)w;  w += (size_t)N_NODES * sizeof(int);
        int* row_ptr   = (int*)w;  w += (size_t)(N_NODES + 1) * sizeof(int);
        int* blockSums = (int*)w;  w += (size_t)N_SCAN_BLOCKS * sizeof(int);
        int* blockOffs = (int*)w;  w += (size_t)N_SCAN_BLOCKS * sizeof(int);
        w = (char*)(((uintptr_t)w + 15) & ~(uintptr_t)15);
        unsigned* s_edges = (unsigned*)w;  w += (size_t)N_EDGES * sizeof(unsigned);
        unsigned short* mirrorA = (unsigned short*)w;  w += (size_t)N_NODES * EMB_DIM * sizeof(unsigned short);
        unsigned short* mirrorB = (unsigned short*)w;
        // Phase-A record staging aliases mirrorA+mirrorB (3.2M * 8B = 25.6 MB,
        // exactly the two mirrors). Mirrors are written only AFTER the build.
        uint2* records = (uint2*)mirrorA;

        hipMemsetAsync(counts, 0, (size_t)N_NODES * sizeof(int), stream);
        {
            int block = 256, grid = (N_EDGES + block - 1) / block;
            count_rows<<<grid, block, 0, stream>>>(rows, counts);
        }
        scan_phase1<<<N_SCAN_BLOCKS, SCAN_BLOCK, 0, stream>>>(counts, blockSums);
        scan_phase2<<<1, 256, 0, stream>>>(blockSums, blockOffs, row_ptr);
        scan_phase3<<<N_SCAN_BLOCKS, SCAN_BLOCK, 0, stream>>>(counts, blockOffs, row_ptr);
        // counts array is free now -> reuse first 16 KB as bucketFill.
        int* bucketFill = counts;
        hipMemsetAsync(bucketFill, 0, (size_t)NB_BUCKETS * sizeof(int), stream);
        {
            int block = 256, grid = (N_EDGES + block - 1) / block;
            build_phaseA<<<grid, block, 0, stream>>>(rows, cols, vals, row_ptr, bucketFill, records);
        }
        build_phaseB<<<NB_BUCKETS, 256, 0, stream>>>(row_ptr, records, s_edges);
        {
            int total = N_NODES * 16;
            int block = 256, grid = (total + block - 1) / block;
            emb_to_bf16<<<grid, block, 0, stream>>>(emb, (ushort4*)mirrorA);
        }
        {
            long long threads = (long long)N_NODES * 64;
            int block = 256;
            int grid = (int)((threads + block - 1) / block);
            spmm_gather_bf16_mid<<<grid, block, 0, stream>>>(row_ptr, s_edges, mirrorA, stacked + 1 * 64, mirrorB);
            spmm_gather_bf16_mid<<<grid, block, 0, stream>>>(row_ptr, s_edges, mirrorB, stacked + 2 * 64, mirrorA);
            spmm_gather_bf16_last<<<grid, block, 0, stream>>>(row_ptr, s_edges, mirrorA, emb, stacked, meanOut);
        }
    } else if (ws_size >= need_f32) {
        char* w = (char*)d_ws;
        int* counts    = (int*)w;  w += (size_t)N_NODES * sizeof(int);
        int* row_ptr   = (int*)w;  w += (size_t)(N_NODES + 1) * sizeof(int);
        int* blockSums = (int*)w;  w += (size_t)N_SCAN_BLOCKS * sizeof(int);
        int* blockOffs = (int*)w;  w += (size_t)N_SCAN_BLOCKS * sizeof(int);
        w = (char*)(((uintptr_t)w + 15) & ~(uintptr_t)15);
        int2* s_colval = (int2*)w;

        hipMemsetAsync(counts, 0, (size_t)N_NODES * sizeof(int), stream);
        {
            int block = 256, grid = (N_EDGES + block - 1) / block;
            count_rows<<<grid, block, 0, stream>>>(rows, counts);
        }
        scan_phase1<<<N_SCAN_BLOCKS, SCAN_BLOCK, 0, stream>>>(counts, blockSums);
        scan_phase2<<<1, 256, 0, stream>>>(blockSums, blockOffs, row_ptr);
        scan_phase3<<<N_SCAN_BLOCKS, SCAN_BLOCK, 0, stream>>>(counts, blockOffs, row_ptr);
        hipMemsetAsync(counts, 0, (size_t)N_NODES * sizeof(int), stream);
        {
            int block = 256, grid = (N_EDGES + block - 1) / block;
            scatter_edges_int2<<<grid, block, 0, stream>>>(rows, cols, vals, row_ptr, counts, s_colval);
        }
        {
            long long threads = (long long)N_NODES * 64;
            int block = 256;
            int grid = (int)((threads + block - 1) / block);
            spmm_gather_f32<<<grid, block, 0, stream>>>(row_ptr, s_colval, emb, 64, stacked + 1 * 64);
            spmm_gather_f32<<<grid, block, 0, stream>>>(row_ptr, s_colval, stacked + 1 * 64, 256, stacked + 2 * 64);
            spmm_gather_f32<<<grid, block, 0, stream>>>(row_ptr, s_colval, stacked + 2 * 64, 256, stacked + 3 * 64);
        }
        {
            int total = N_NODES * 16;
            int block = 256, grid = (total + block - 1) / block;
            mean_layers<<<grid, block, 0, stream>>>(emb, stacked, meanOut);
        }
    } else {
        {
            int total = N_NODES * 64;
            int block = 256, grid = (total + block - 1) / block;
            init_stacked_full<<<grid, block, 0, stream>>>(emb, stacked);
        }
        {
            long long total = (long long)N_EDGES * 16;
            int block = 256, grid = (int)((total + block - 1) / block);
            for (int l = 0; l < N_LAYERS; ++l)
                spmm_atomic<<<grid, block, 0, stream>>>(rows, cols, vals, stacked, l);
        }
        {
            int total = N_NODES * 16;
            int block = 256, grid = (total + block - 1) / block;
            mean_layers_plain<<<grid, block, 0, stream>>>(stacked, meanOut);
        }
    }
}

// Round 4
// 674.663 us; speedup vs baseline: 1.1896x; 1.1896x over previous
//
#include <hip/hip_runtime.h>
#include <hip/hip_fp16.h>

#define N_NODES 100000
#define EMB_DIM 64
#define N_EDGES 3200000
#define N_LAYERS 3

#define SCAN_BLOCK 512
#define N_SCAN_BLOCKS ((N_NODES + SCAN_BLOCK - 1) / SCAN_BLOCK)   // 196

// Coarse bins for the two-phase CSR build.
#define ABINROWS 256
#define NBINS ((N_NODES + ABINROWS - 1) / ABINROWS)   // 391
#define NBINS_P 512
#define ACHUNK 4096
#define NCHUNKS ((N_EDGES + ACHUNK - 1) / ACHUNK)     // 782

// d_out layout: mean [N_NODES*64] first, then stacked [N_NODES*4*64]
// stacked[n][l][d] at n*256 + l*64 + d

__device__ __forceinline__ unsigned short f32_to_bf16_rtn(float f) {
    unsigned u = __float_as_uint(f);
    unsigned r = u + 0x7FFFu + ((u >> 16) & 1u);
    return (unsigned short)(r >> 16);
}
__device__ __forceinline__ float bf16_to_f32(unsigned short h) {
    return __uint_as_float(((unsigned)h) << 16);
}

// ---------- CSR build: row counts + scan ----------

__global__ void count_rows(const int* __restrict__ rows, int* __restrict__ counts) {
    int e = blockIdx.x * blockDim.x + threadIdx.x;
    if (e >= N_EDGES) return;
    atomicAdd(&counts[rows[e]], 1);
}

__global__ void __launch_bounds__(SCAN_BLOCK) scan_phase1(const int* __restrict__ counts,
                                                          int* __restrict__ blockSums) {
    __shared__ int sm[SCAN_BLOCK];
    int idx = blockIdx.x * SCAN_BLOCK + threadIdx.x;
    int v = (idx < N_NODES) ? counts[idx] : 0;
    sm[threadIdx.x] = v;
    __syncthreads();
    for (int off = SCAN_BLOCK / 2; off > 0; off >>= 1) {
        if (threadIdx.x < off) sm[threadIdx.x] += sm[threadIdx.x + off];
        __syncthreads();
    }
    if (threadIdx.x == 0) blockSums[blockIdx.x] = sm[0];
}

__global__ void __launch_bounds__(256) scan_phase2(const int* __restrict__ blockSums,
                                                   int* __restrict__ blockOffs,
                                                   int* __restrict__ row_ptr) {
    __shared__ int sm[256];
    int t = threadIdx.x;
    int v = (t < N_SCAN_BLOCKS) ? blockSums[t] : 0;
    sm[t] = v;
    __syncthreads();
    for (int off = 1; off < 256; off <<= 1) {
        int u = (t >= off) ? sm[t - off] : 0;
        __syncthreads();
        sm[t] += u;
        __syncthreads();
    }
    if (t < N_SCAN_BLOCKS) blockOffs[t] = (t == 0) ? 0 : sm[t - 1];
    if (t == 255) row_ptr[N_NODES] = sm[255];
}

__global__ void __launch_bounds__(SCAN_BLOCK) scan_phase3(const int* __restrict__ counts,
                                                          const int* __restrict__ blockOffs,
                                                          int* __restrict__ row_ptr) {
    __shared__ int sm[SCAN_BLOCK];
    int idx = blockIdx.x * SCAN_BLOCK + threadIdx.x;
    int t = threadIdx.x;
    int v = (idx < N_NODES) ? counts[idx] : 0;
    sm[t] = v;
    __syncthreads();
    for (int off = 1; off < SCAN_BLOCK; off <<= 1) {
        int u = (t >= off) ? sm[t - off] : 0;
        __syncthreads();
        sm[t] += u;
        __syncthreads();
    }
    if (idx < N_NODES) row_ptr[idx] = blockOffs[blockIdx.x] + sm[t] - v;
}

// ---------- phase A: LDS counting-sort partition (dense run writes) ----------
// Each WG counting-sorts 4096 edges by bin (row>>8) in LDS, reserves one
// contiguous run per non-empty bin with a single atomicAdd, and copies runs
// out with coalesced contiguous writes. Write amplification ~= one partial
// line per run boundary instead of one line per record.
// Packed edge: col (17 bits) << 15 | fp16(val) low 15 bits (val>=0 so sign=0).

__global__ void __launch_bounds__(256) build_sortA(const int* __restrict__ rows,
                                                   const int* __restrict__ cols,
                                                   const float* __restrict__ vals,
                                                   const int* __restrict__ row_ptr,
                                                   int* __restrict__ bucketFill,
                                                   uint2* __restrict__ records) {
    __shared__ int binCnt[NBINS_P];
    __shared__ int binInc[NBINS_P];   // inclusive prefix of binCnt
    __shared__ int binCur[NBINS_P];
    __shared__ int binG[NBINS];       // global dst base of this WG's run per bin
    __shared__ uint2 buf[ACHUNK];     // bin-sorted records

    int base = blockIdx.x * ACHUNK;
    int n = N_EDGES - base; if (n > ACHUNK) n = ACHUNK;
    int t = threadIdx.x;

    for (int i = t; i < NBINS_P; i += 256) { binCnt[i] = 0; binCur[i] = 0; }
    __syncthreads();

    // Load 16 edges/thread (static unroll -> registers, no scratch) + histogram.
    int r_[16]; unsigned pk_[16];
#pragma unroll 16
    for (int k = 0; k < 16; ++k) {
        int i = t + k * 256;
        r_[k] = 0; pk_[k] = 0;
        if (i < n) {
            int e = base + i;
            int r = rows[e];
            unsigned hb = __half_as_ushort(__float2half(vals[e]));
            r_[k] = r;
            pk_[k] = (((unsigned)cols[e]) << 15) | (hb & 0x7FFFu);
            atomicAdd(&binCnt[r >> 8], 1);
        }
    }
    __syncthreads();

    // Hillis-Steele inclusive scan over NBINS_P entries (2 per thread).
    binInc[t] = binCnt[t];
    binInc[t + 256] = binCnt[t + 256];
    __syncthreads();
    for (int off = 1; off < NBINS_P; off <<= 1) {
        int i0 = t, i1 = t + 256;
        int v0 = (i0 >= off) ? binInc[i0 - off] : 0;
        int v1 = (i1 >= off) ? binInc[i1 - off] : 0;
        __syncthreads();
        binInc[i0] += v0;
        binInc[i1] += v1;
        __syncthreads();
    }

    // Scatter records into LDS at bin-sorted positions.
#pragma unroll 16
    for (int k = 0; k < 16; ++k) {
        int i = t + k * 256;
        if (i < n) {
            int b = r_[k] >> 8;
            int slot = (binInc[b] - binCnt[b]) + atomicAdd(&binCur[b], 1);
            buf[slot] = make_uint2((unsigned)r_[k], pk_[k]);
        }
    }
    // One global reservation per non-empty bin.
    for (int b = t; b < NBINS; b += 256) {
        int c = binCnt[b];
        if (c > 0) binG[b] = row_ptr[b * ABINROWS] + atomicAdd(&bucketFill[b], c);
    }
    __syncthreads();

    // Coalesced copy-out: consecutive p within a run -> consecutive global dst.
    for (int p = t; p < n; p += 256) {
        uint2 rec = buf[p];
        int b = (int)(rec.x >> 8);
        int dst = binG[b] + (p - (binInc[b] - binCnt[b]));
        records[dst] = rec;
    }
}

// ---------- phase B: per-bin scatter to exact CSR slots (L2-resident window) ----------
__global__ void __launch_bounds__(256) build_phaseB(const int* __restrict__ row_ptr,
                                                    const uint2* __restrict__ records,
                                                    unsigned* __restrict__ s_edges) {
    __shared__ int lfill[ABINROWS];
    __shared__ int lrp[ABINROWS];
    int b = blockIdx.x;
    int r0 = b * ABINROWS;
    int r1 = r0 + ABINROWS; if (r1 > N_NODES) r1 = N_NODES;
    int nr = r1 - r0;
    for (int i = threadIdx.x; i < nr; i += 256) { lfill[i] = 0; lrp[i] = row_ptr[r0 + i]; }
    __syncthreads();
    int beg = row_ptr[r0];
    int end = row_ptr[r1];
    for (int i = beg + threadIdx.x; i < end; i += 256) {
        uint2 rec = records[i];
        int lr = (int)rec.x - r0;
        int lp = atomicAdd(&lfill[lr], 1);
        s_edges[lrp[lr] + lp] = rec.y;
    }
}

// ---------- emb -> bf16 mirror ----------
__global__ void emb_to_bf16(const float* __restrict__ emb, ushort4* __restrict__ mirror) {
    int t = blockIdx.x * blockDim.x + threadIdx.x;   // [0, N_NODES*16)
    if (t >= N_NODES * 16) return;
    float4 v = ((const float4*)emb)[t];
    ushort4 o;
    o.x = f32_to_bf16_rtn(v.x); o.y = f32_to_bf16_rtn(v.y);
    o.z = f32_to_bf16_rtn(v.z); o.w = f32_to_bf16_rtn(v.w);
    mirror[t] = o;
}

// ---------- SpMM gather core, bf16 source: one wave per destination node ----------
// 4 groups x 16 lanes; lane j of a group owns bf16x4 chunk j of the 64-dim row.
// Edge words staged via ONE coalesced per-lane load, distributed with __shfl.
// Control flow is wave-uniform (shfl from inactive lanes is undefined on CDNA).

__device__ __forceinline__ void gacc(float4& acc, unsigned p, int j,
                                     const unsigned short* __restrict__ srcMirror) {
    float v = __half2float(__ushort_as_half((unsigned short)(p & 0x7FFFu)));
    ushort4 m = *(const ushort4*)(srcMirror + (size_t)(p >> 15) * 64 + j * 4);
    acc.x += v * bf16_to_f32(m.x);
    acc.y += v * bf16_to_f32(m.y);
    acc.z += v * bf16_to_f32(m.z);
    acc.w += v * bf16_to_f32(m.w);
}

__device__ __forceinline__ float4 spmm_row_core(int beg, int end, int g, int j, int lane,
                                                const unsigned* __restrict__ s_edges,
                                                const unsigned short* __restrict__ srcMirror) {
    int deg = end - beg;                  // wave-uniform
    unsigned ew = (lane < deg) ? s_edges[beg + lane] : 0u;
    float4 acc = make_float4(0.f, 0.f, 0.f, 0.f);
    int nfull = deg < 64 ? deg : 64;      // wave-uniform
    for (int kb = 0; kb < nfull; kb += 16) {
        int k0 = kb + g, k1 = kb + g + 4, k2 = kb + g + 8, k3 = kb + g + 12;
        unsigned p0 = __shfl(ew, k0);
        unsigned p1 = __shfl(ew, k1);
        unsigned p2 = __shfl(ew, k2);
        unsigned p3 = __shfl(ew, k3);
        if (k0 < nfull) gacc(acc, p0, j, srcMirror);
        if (k1 < nfull) gacc(acc, p1, j, srcMirror);
        if (k2 < nfull) gacc(acc, p2, j, srcMirror);
        if (k3 < nfull) gacc(acc, p3, j, srcMirror);
    }
    for (int e = beg + 64 + g; e < end; e += 4) {
        unsigned p = s_edges[e];
        gacc(acc, p, j, srcMirror);
    }
    acc.x += __shfl_xor(acc.x, 16); acc.y += __shfl_xor(acc.y, 16);
    acc.z += __shfl_xor(acc.z, 16); acc.w += __shfl_xor(acc.w, 16);
    acc.x += __shfl_xor(acc.x, 32); acc.y += __shfl_xor(acc.y, 32);
    acc.z += __shfl_xor(acc.z, 32); acc.w += __shfl_xor(acc.w, 32);
    return acc;
}

__global__ void __launch_bounds__(256) spmm_gather_bf16_mid(const int* __restrict__ row_ptr,
                                                            const unsigned* __restrict__ s_edges,
                                                            const unsigned short* __restrict__ srcMirror,
                                                            float* __restrict__ dstStacked,
                                                            unsigned short* __restrict__ dstMirror) {
    int wave = (blockIdx.x * blockDim.x + threadIdx.x) >> 6;
    if (wave >= N_NODES) return;
    int lane = threadIdx.x & 63;
    int g = lane >> 4, j = lane & 15;
    float4 acc = spmm_row_core(row_ptr[wave], row_ptr[wave + 1], g, j, lane, s_edges, srcMirror);
    if (lane < 16) {
        *(float4*)(dstStacked + (size_t)wave * 256 + j * 4) = acc;
        ushort4 o;
        o.x = f32_to_bf16_rtn(acc.x); o.y = f32_to_bf16_rtn(acc.y);
        o.z = f32_to_bf16_rtn(acc.z); o.w = f32_to_bf16_rtn(acc.w);
        *(ushort4*)(dstMirror + (size_t)wave * 64 + j * 4) = o;
    }
}

// Last layer: fuse the 4-layer mean + layer-0 copy into the same dispatch.
__global__ void __launch_bounds__(256) spmm_gather_bf16_last(const int* __restrict__ row_ptr,
                                                             const unsigned* __restrict__ s_edges,
                                                             const unsigned short* __restrict__ srcMirror,
                                                             const float* __restrict__ emb,
                                                             float* __restrict__ stacked,
                                                             float* __restrict__ meanOut) {
    int wave = (blockIdx.x * blockDim.x + threadIdx.x) >> 6;
    if (wave >= N_NODES) return;
    int lane = threadIdx.x & 63;
    int g = lane >> 4, j = lane & 15;
    float4 acc = spmm_row_core(row_ptr[wave], row_ptr[wave + 1], g, j, lane, s_edges, srcMirror);
    if (lane < 16) {
        float4* base = (float4*)stacked + (size_t)wave * 64;
        float4 a = ((const float4*)emb)[wave * 16 + j];
        float4 b = base[16 + j];
        float4 c = base[32 + j];
        base[j] = a;          // layer 0
        base[48 + j] = acc;   // layer 3
        float4 s;
        s.x = 0.25f * (a.x + b.x + c.x + acc.x);
        s.y = 0.25f * (a.y + b.y + c.y + acc.y);
        s.z = 0.25f * (a.z + b.z + c.z + acc.z);
        s.w = 0.25f * (a.w + b.w + c.w + acc.w);
        ((float4*)meanOut)[wave * 16 + j] = s;
    }
}

// ---------- mean over 4 layers (f32 fallback path) ----------
__global__ void mean_layers(const float* __restrict__ emb,
                            float* __restrict__ stacked,
                            float* __restrict__ meanOut) {
    int t = blockIdx.x * blockDim.x + threadIdx.x;   // [0, N_NODES*16)
    if (t >= N_NODES * 16) return;
    int n = t >> 4;
    int j = t & 15;
    float4* base = (float4*)stacked + (size_t)n * 64;
    float4 a = ((const float4*)emb)[t];
    float4 b = base[16 + j];
    float4 c = base[32 + j];
    float4 d = base[48 + j];
    base[j] = a;
    float4 s;
    s.x = 0.25f * (a.x + b.x + c.x + d.x);
    s.y = 0.25f * (a.y + b.y + c.y + d.y);
    s.z = 0.25f * (a.z + b.z + c.z + d.z);
    s.w = 0.25f * (a.w + b.w + c.w + d.w);
    ((float4*)meanOut)[t] = s;
}

// ---------- mid fallback: fp32 CSR gather ----------

__global__ void scatter_edges_int2(const int* __restrict__ rows, const int* __restrict__ cols,
                                   const float* __restrict__ vals,
                                   const int* __restrict__ row_ptr, int* __restrict__ fill,
                                   int2* __restrict__ s_colval) {
    int e = blockIdx.x * blockDim.x + threadIdx.x;
    if (e >= N_EDGES) return;
    int r = rows[e];
    int pos = row_ptr[r] + atomicAdd(&fill[r], 1);
    int2 p; p.x = cols[e]; p.y = __float_as_int(vals[e]);
    s_colval[pos] = p;
}

__global__ void __launch_bounds__(256) spmm_gather_f32(const int* __restrict__ row_ptr,
                                                       const int2* __restrict__ s_colval,
                                                       const float* __restrict__ src, int srcStride,
                                                       float* __restrict__ dst) {
    int wave = (blockIdx.x * blockDim.x + threadIdx.x) >> 6;
    if (wave >= N_NODES) return;
    int lane = threadIdx.x & 63;
    int g = lane >> 4, j = lane & 15;
    int beg = row_ptr[wave], end = row_ptr[wave + 1];
    float4 acc = make_float4(0.f, 0.f, 0.f, 0.f);
    int e = beg + g;
    for (; e + 4 < end; e += 8) {
        int2 p0 = s_colval[e], p1 = s_colval[e + 4];
        float v0 = __int_as_float(p0.y), v1 = __int_as_float(p1.y);
        float4 m0 = *(const float4*)(src + (size_t)p0.x * srcStride + j * 4);
        float4 m1 = *(const float4*)(src + (size_t)p1.x * srcStride + j * 4);
        acc.x += v0 * m0.x + v1 * m1.x; acc.y += v0 * m0.y + v1 * m1.y;
        acc.z += v0 * m0.z + v1 * m1.z; acc.w += v0 * m0.w + v1 * m1.w;
    }
    for (; e < end; e += 4) {
        int2 p = s_colval[e];
        float v = __int_as_float(p.y);
        float4 m = *(const float4*)(src + (size_t)p.x * srcStride + j * 4);
        acc.x += v * m.x; acc.y += v * m.y; acc.z += v * m.z; acc.w += v * m.w;
    }
    acc.x += __shfl_xor(acc.x, 16); acc.y += __shfl_xor(acc.y, 16);
    acc.z += __shfl_xor(acc.z, 16); acc.w += __shfl_xor(acc.w, 16);
    acc.x += __shfl_xor(acc.x, 32); acc.y += __shfl_xor(acc.y, 32);
    acc.z += __shfl_xor(acc.z, 32); acc.w += __shfl_xor(acc.w, 32);
    if (lane < 16)
        *(float4*)(dst + (size_t)wave * 256 + j * 4) = acc;
}

// ---------- last fallback: atomic scatter ----------

__global__ void init_stacked_full(const float* __restrict__ emb, float* __restrict__ stacked) {
    int t = blockIdx.x * blockDim.x + threadIdx.x;
    if (t >= N_NODES * 64) return;
    int n = t >> 6, j = t & 63;
    float4 v = (j < 16) ? ((const float4*)emb)[n * 16 + j] : make_float4(0.f, 0.f, 0.f, 0.f);
    ((float4*)stacked)[n * 64 + j] = v;
}

__global__ void spmm_atomic(const int* __restrict__ rows, const int* __restrict__ cols,
                            const float* __restrict__ vals, float* __restrict__ stacked,
                            int lprev) {
    int t = blockIdx.x * blockDim.x + threadIdx.x;
    int e = t >> 4, j = t & 15;
    if (e >= N_EDGES) return;
    int r = rows[e], c = cols[e];
    float v = vals[e];
    const float4* src = (const float4*)(stacked + (size_t)c * 256 + lprev * 64);
    float4 m = src[j];
    float* dst = stacked + (size_t)r * 256 + (lprev + 1) * 64 + j * 4;
    atomicAdd(dst + 0, v * m.x); atomicAdd(dst + 1, v * m.y);
    atomicAdd(dst + 2, v * m.z); atomicAdd(dst + 3, v * m.w);
}

__global__ void mean_layers_plain(const float* __restrict__ stacked, float* __restrict__ meanOut) {
    int t = blockIdx.x * blockDim.x + threadIdx.x;
    if (t >= N_NODES * 16) return;
    int n = t >> 4, j = t & 15;
    const float4* base = (const float4*)(stacked + (size_t)n * 256);
    float4 a = base[j], b = base[16 + j], c = base[32 + j], d = base[48 + j];
    float4 s;
    s.x = 0.25f * (a.x + b.x + c.x + d.x);
    s.y = 0.25f * (a.y + b.y + c.y + d.y);
    s.z = 0.25f * (a.z + b.z + c.z + d.z);
    s.w = 0.25f * (a.w + b.w + c.w + d.w);
    ((float4*)meanOut)[t] = s;
}

extern "C" void kernel_launch(void* const* d_in, const int* in_sizes, int n_in,
                              void* d_out, int out_size, void* d_ws, size_t ws_size,
                              hipStream_t stream) {
    const float* emb  = (const float*)d_in[0];
    const int*   rows = (const int*)d_in[1];
    const int*   cols = (const int*)d_in[2];
    const float* vals = (const float*)d_in[3];

    float* meanOut = (float*)d_out;
    float* stacked = (float*)d_out + (size_t)N_NODES * EMB_DIM;

    const size_t headInts = (size_t)(N_NODES * 2 + 1 + 2 * N_SCAN_BLOCKS);
    size_t need_bf16 = headInts * sizeof(int) + 64
                     + (size_t)N_EDGES * sizeof(unsigned)
                     + 2 * (size_t)N_NODES * EMB_DIM * sizeof(unsigned short);
    size_t need_f32  = headInts * sizeof(int) + 64 + (size_t)N_EDGES * sizeof(int2);

    if (ws_size >= need_bf16) {
        char* w = (char*)d_ws;
        int* counts    = (int*)w;  w += (size_t)N_NODES * sizeof(int);
        int* row_ptr   = (int*)w;  w += (size_t)(N_NODES + 1) * sizeof(int);
        int* blockSums = (int*)w;  w += (size_t)N_SCAN_BLOCKS * sizeof(int);
        int* blockOffs = (int*)w;  w += (size_t)N_SCAN_BLOCKS * sizeof(int);
        w = (char*)(((uintptr_t)w + 15) & ~(uintptr_t)15);
        unsigned* s_edges = (unsigned*)w;  w += (size_t)N_EDGES * sizeof(unsigned);
        unsigned short* mirrorA = (unsigned short*)w;  w += (size_t)N_NODES * EMB_DIM * sizeof(unsigned short);
        unsigned short* mirrorB = (unsigned short*)w;
        // Phase-A record staging aliases mirrorA+mirrorB (3.2M * 8B = 25.6 MB,
        // exactly the two mirrors). Mirrors are written only AFTER the build.
        uint2* records = (uint2*)mirrorA;

        hipMemsetAsync(counts, 0, (size_t)N_NODES * sizeof(int), stream);
        {
            int block = 256, grid = (N_EDGES + block - 1) / block;
            count_rows<<<grid, block, 0, stream>>>(rows, counts);
        }
        scan_phase1<<<N_SCAN_BLOCKS, SCAN_BLOCK, 0, stream>>>(counts, blockSums);
        scan_phase2<<<1, 256, 0, stream>>>(blockSums, blockOffs, row_ptr);
        scan_phase3<<<N_SCAN_BLOCKS, SCAN_BLOCK, 0, stream>>>(counts, blockOffs, row_ptr);
        // counts array is free now -> reuse as bucketFill (NBINS ints).
        int* bucketFill = counts;
        hipMemsetAsync(bucketFill, 0, (size_t)NBINS * sizeof(int), stream);
        build_sortA<<<NCHUNKS, 256, 0, stream>>>(rows, cols, vals, row_ptr, bucketFill, records);
        build_phaseB<<<NBINS, 256, 0, stream>>>(row_ptr, records, s_edges);
        {
            int total = N_NODES * 16;
            int block = 256, grid = (total + block - 1) / block;
            emb_to_bf16<<<grid, block, 0, stream>>>(emb, (ushort4*)mirrorA);
        }
        {
            long long threads = (long long)N_NODES * 64;
            int block = 256;
            int grid = (int)((threads + block - 1) / block);
            spmm_gather_bf16_mid<<<grid, block, 0, stream>>>(row_ptr, s_edges, mirrorA, stacked + 1 * 64, mirrorB);
            spmm_gather_bf16_mid<<<grid, block, 0, stream>>>(row_ptr, s_edges, mirrorB, stacked + 2 * 64, mirrorA);
            spmm_gather_bf16_last<<<grid, block, 0, stream>>>(row_ptr, s_edges, mirrorA, emb, stacked, meanOut);
        }
    } else if (ws_size >= need_f32) {
        char* w = (char*)d_ws;
        int* counts    = (int*)w;  w += (size_t)N_NODES * sizeof(int);
        int* row_ptr   = (int*)w;  w += (size_t)(N_NODES + 1) * sizeof(int);
        int* blockSums = (int*)w;  w += (size_t)N_SCAN_BLOCKS * sizeof(int);
        int* blockOffs = (int*)w;  w += (size_t)N_SCAN_BLOCKS * sizeof(int);
        w = (char*)(((uintptr_t)w + 15) & ~(uintptr_t)15);
        int2* s_colval = (int2*)w;

        hipMemsetAsync(counts, 0, (size_t)N_NODES * sizeof(int), stream);
        {
            int block = 256, grid = (N_EDGES + block - 1) / block;
            count_rows<<<grid, block, 0, stream>>>(rows, counts);
        }
        scan_phase1<<<N_SCAN_BLOCKS, SCAN_BLOCK, 0, stream>>>(counts, blockSums);
        scan_phase2<<<1, 256, 0, stream>>>(blockSums, blockOffs, row_ptr);
        scan_phase3<<<N_SCAN_BLOCKS, SCAN_BLOCK, 0, stream>>>(counts, blockOffs, row_ptr);
        hipMemsetAsync(counts, 0, (size_t)N_NODES * sizeof(int), stream);
        {
            int block = 256, grid = (N_EDGES + block - 1) / block;
            scatter_edges_int2<<<grid, block, 0, stream>>>(rows, cols, vals, row_ptr, counts, s_colval);
        }
        {
            long long threads = (long long)N_NODES * 64;
            int block = 256;
            int grid = (int)((threads + block - 1) / block);
            spmm_gather_f32<<<grid, block, 0, stream>>>(row_ptr, s_colval, emb, 64, stacked + 1 * 64);
            spmm_gather_f32<<<grid, block, 0, stream>>>(row_ptr, s_colval, stacked + 1 * 64, 256, stacked + 2 * 64);
            spmm_gather_f32<<<grid, block, 0, stream>>>(row_ptr, s_colval, stacked + 2 * 64, 256, stacked + 3 * 64);
        }
        {
            int total = N_NODES * 16;
            int block = 256, grid = (total + block - 1) / block;
            mean_layers<<<grid, block, 0, stream>>>(emb, stacked, meanOut);
        }
    } else {
        {
            int total = N_NODES * 64;
            int block = 256, grid = (total + block - 1) / block;
            init_stacked_full<<<grid, block, 0, stream>>>(emb, stacked);
        }
        {
            long long total = (long long)N_EDGES * 16;
            int block = 256, grid = (int)((total + block - 1) / block);
            for (int l = 0; l < N_LAYERS; ++l)
                spmm_atomic<<<grid, block, 0, stream>>>(rows, cols, vals, stacked, l);
        }
        {
            int total = N_NODES * 16;
            int block = 256, grid = (total + block - 1) / block;
            mean_layers_plain<<<grid, block, 0, stream>>>(stacked, meanOut);
        }
    }
}

// Round 5
// 650.016 us; speedup vs baseline: 1.2347x; 1.0379x over previous
//
#include <hip/hip_runtime.h>
#include <hip/hip_fp16.h>

#define N_NODES 100000
#define EMB_DIM 64
#define N_EDGES 3200000
#define N_LAYERS 3

#define SCAN_BLOCK 512
#define N_SCAN_BLOCKS ((N_NODES + SCAN_BLOCK - 1) / SCAN_BLOCK)   // 196

// Coarse bins for the two-phase CSR build.
#define ABINROWS 256
#define NBINS ((N_NODES + ABINROWS - 1) / ABINROWS)   // 391
#define NBINS_P 512
#define ACHUNK 2048          // R4: was 4096; halved to fix occupancy (VGPR 220->~120, LDS 40->24KB)
#define AEPT 8               // edges staged per thread (static unroll -> registers)
#define NCHUNKS ((N_EDGES + ACHUNK - 1) / ACHUNK)     // 1563

// d_out layout: mean [N_NODES*64] first, then stacked [N_NODES*4*64]
// stacked[n][l][d] at n*256 + l*64 + d

__device__ __forceinline__ unsigned short f32_to_bf16_rtn(float f) {
    unsigned u = __float_as_uint(f);
    unsigned r = u + 0x7FFFu + ((u >> 16) & 1u);
    return (unsigned short)(r >> 16);
}
__device__ __forceinline__ float bf16_to_f32(unsigned short h) {
    return __uint_as_float(((unsigned)h) << 16);
}

// ---------- CSR build: row counts + scan ----------

__global__ void count_rows(const int* __restrict__ rows, int* __restrict__ counts) {
    int e = blockIdx.x * blockDim.x + threadIdx.x;
    if (e >= N_EDGES) return;
    atomicAdd(&counts[rows[e]], 1);
}

__global__ void __launch_bounds__(SCAN_BLOCK) scan_phase1(const int* __restrict__ counts,
                                                          int* __restrict__ blockSums) {
    __shared__ int sm[SCAN_BLOCK];
    int idx = blockIdx.x * SCAN_BLOCK + threadIdx.x;
    int v = (idx < N_NODES) ? counts[idx] : 0;
    sm[threadIdx.x] = v;
    __syncthreads();
    for (int off = SCAN_BLOCK / 2; off > 0; off >>= 1) {
        if (threadIdx.x < off) sm[threadIdx.x] += sm[threadIdx.x + off];
        __syncthreads();
    }
    if (threadIdx.x == 0) blockSums[blockIdx.x] = sm[0];
}

__global__ void __launch_bounds__(256) scan_phase2(const int* __restrict__ blockSums,
                                                   int* __restrict__ blockOffs,
                                                   int* __restrict__ row_ptr) {
    __shared__ int sm[256];
    int t = threadIdx.x;
    int v = (t < N_SCAN_BLOCKS) ? blockSums[t] : 0;
    sm[t] = v;
    __syncthreads();
    for (int off = 1; off < 256; off <<= 1) {
        int u = (t >= off) ? sm[t - off] : 0;
        __syncthreads();
        sm[t] += u;
        __syncthreads();
    }
    if (t < N_SCAN_BLOCKS) blockOffs[t] = (t == 0) ? 0 : sm[t - 1];
    if (t == 255) row_ptr[N_NODES] = sm[255];
}

__global__ void __launch_bounds__(SCAN_BLOCK) scan_phase3(const int* __restrict__ counts,
                                                          const int* __restrict__ blockOffs,
                                                          int* __restrict__ row_ptr) {
    __shared__ int sm[SCAN_BLOCK];
    int idx = blockIdx.x * SCAN_BLOCK + threadIdx.x;
    int t = threadIdx.x;
    int v = (idx < N_NODES) ? counts[idx] : 0;
    sm[t] = v;
    __syncthreads();
    for (int off = 1; off < SCAN_BLOCK; off <<= 1) {
        int u = (t >= off) ? sm[t - off] : 0;
        __syncthreads();
        sm[t] += u;
        __syncthreads();
    }
    if (idx < N_NODES) row_ptr[idx] = blockOffs[blockIdx.x] + sm[t] - v;
}

// ---------- phase A: LDS counting-sort partition (dense run writes) ----------
// Each WG counting-sorts ACHUNK edges by bin (row>>8) in LDS, reserves one
// contiguous run per non-empty bin with a single atomicAdd, and copies runs
// out with coalesced contiguous writes. Runs are WG-owned -> lines merge in
// one XCD's L2; amplification only at run boundaries.
// Packed edge: col (17 bits) << 15 | fp16(val) low 15 bits (val>=0 so sign=0).

__global__ void __launch_bounds__(256) build_sortA(const int* __restrict__ rows,
                                                   const int* __restrict__ cols,
                                                   const float* __restrict__ vals,
                                                   const int* __restrict__ row_ptr,
                                                   int* __restrict__ bucketFill,
                                                   uint2* __restrict__ records) {
    __shared__ int binCnt[NBINS_P];
    __shared__ int binInc[NBINS_P];   // inclusive prefix of binCnt
    __shared__ int binCur[NBINS_P];
    __shared__ int binG[NBINS];       // global dst base of this WG's run per bin
    __shared__ uint2 buf[ACHUNK];     // bin-sorted records

    int base = blockIdx.x * ACHUNK;
    int n = N_EDGES - base; if (n > ACHUNK) n = ACHUNK;
    int t = threadIdx.x;

    for (int i = t; i < NBINS_P; i += 256) { binCnt[i] = 0; binCur[i] = 0; }
    __syncthreads();

    // Load AEPT edges/thread (static unroll -> registers, no scratch) + histogram.
    int r_[AEPT]; unsigned pk_[AEPT];
#pragma unroll AEPT
    for (int k = 0; k < AEPT; ++k) {
        int i = t + k * 256;
        r_[k] = 0; pk_[k] = 0;
        if (i < n) {
            int e = base + i;
            int r = rows[e];
            unsigned hb = __half_as_ushort(__float2half(vals[e]));
            r_[k] = r;
            pk_[k] = (((unsigned)cols[e]) << 15) | (hb & 0x7FFFu);
            atomicAdd(&binCnt[r >> 8], 1);
        }
    }
    __syncthreads();

    // Hillis-Steele inclusive scan over NBINS_P entries (2 per thread).
    binInc[t] = binCnt[t];
    binInc[t + 256] = binCnt[t + 256];
    __syncthreads();
    for (int off = 1; off < NBINS_P; off <<= 1) {
        int i0 = t, i1 = t + 256;
        int v0 = (i0 >= off) ? binInc[i0 - off] : 0;
        int v1 = (i1 >= off) ? binInc[i1 - off] : 0;
        __syncthreads();
        binInc[i0] += v0;
        binInc[i1] += v1;
        __syncthreads();
    }

    // Scatter records into LDS at bin-sorted positions.
#pragma unroll AEPT
    for (int k = 0; k < AEPT; ++k) {
        int i = t + k * 256;
        if (i < n) {
            int b = r_[k] >> 8;
            int slot = (binInc[b] - binCnt[b]) + atomicAdd(&binCur[b], 1);
            buf[slot] = make_uint2((unsigned)r_[k], pk_[k]);
        }
    }
    // One global reservation per non-empty bin.
    for (int b = t; b < NBINS; b += 256) {
        int c = binCnt[b];
        if (c > 0) binG[b] = row_ptr[b * ABINROWS] + atomicAdd(&bucketFill[b], c);
    }
    __syncthreads();

    // Coalesced copy-out: consecutive p within a run -> consecutive global dst.
    for (int p = t; p < n; p += 256) {
        uint2 rec = buf[p];
        int b = (int)(rec.x >> 8);
        int dst = binG[b] + (p - (binInc[b] - binCnt[b]));
        records[dst] = rec;
    }
}

// ---------- phase B: per-bin scatter to exact CSR slots (L2-resident window) ----------
__global__ void __launch_bounds__(256) build_phaseB(const int* __restrict__ row_ptr,
                                                    const uint2* __restrict__ records,
                                                    unsigned* __restrict__ s_edges) {
    __shared__ int lfill[ABINROWS];
    __shared__ int lrp[ABINROWS];
    int b = blockIdx.x;
    int r0 = b * ABINROWS;
    int r1 = r0 + ABINROWS; if (r1 > N_NODES) r1 = N_NODES;
    int nr = r1 - r0;
    for (int i = threadIdx.x; i < nr; i += 256) { lfill[i] = 0; lrp[i] = row_ptr[r0 + i]; }
    __syncthreads();
    int beg = row_ptr[r0];
    int end = row_ptr[r1];
    for (int i = beg + threadIdx.x; i < end; i += 256) {
        uint2 rec = records[i];
        int lr = (int)rec.x - r0;
        int lp = atomicAdd(&lfill[lr], 1);
        s_edges[lrp[lr] + lp] = rec.y;
    }
}

// ---------- emb -> bf16 mirror ----------
__global__ void emb_to_bf16(const float* __restrict__ emb, ushort4* __restrict__ mirror) {
    int t = blockIdx.x * blockDim.x + threadIdx.x;   // [0, N_NODES*16)
    if (t >= N_NODES * 16) return;
    float4 v = ((const float4*)emb)[t];
    ushort4 o;
    o.x = f32_to_bf16_rtn(v.x); o.y = f32_to_bf16_rtn(v.y);
    o.z = f32_to_bf16_rtn(v.z); o.w = f32_to_bf16_rtn(v.w);
    mirror[t] = o;
}

// ---------- SpMM gather core, bf16 source: one wave per destination node ----------
// 4 groups x 16 lanes; lane j of a group owns bf16x4 chunk j of the 64-dim row.
// Edge words staged via ONE coalesced per-lane load, distributed with __shfl.
// Control flow is wave-uniform (shfl from inactive lanes is undefined on CDNA).

__device__ __forceinline__ void gacc(float4& acc, unsigned p, int j,
                                     const unsigned short* __restrict__ srcMirror) {
    float v = __half2float(__ushort_as_half((unsigned short)(p & 0x7FFFu)));
    ushort4 m = *(const ushort4*)(srcMirror + (size_t)(p >> 15) * 64 + j * 4);
    acc.x += v * bf16_to_f32(m.x);
    acc.y += v * bf16_to_f32(m.y);
    acc.z += v * bf16_to_f32(m.z);
    acc.w += v * bf16_to_f32(m.w);
}

__device__ __forceinline__ float4 spmm_row_core(int beg, int end, int g, int j, int lane,
                                                const unsigned* __restrict__ s_edges,
                                                const unsigned short* __restrict__ srcMirror) {
    int deg = end - beg;                  // wave-uniform
    unsigned ew = (lane < deg) ? s_edges[beg + lane] : 0u;
    float4 acc = make_float4(0.f, 0.f, 0.f, 0.f);
    int nfull = deg < 64 ? deg : 64;      // wave-uniform
    for (int kb = 0; kb < nfull; kb += 16) {
        int k0 = kb + g, k1 = kb + g + 4, k2 = kb + g + 8, k3 = kb + g + 12;
        unsigned p0 = __shfl(ew, k0);
        unsigned p1 = __shfl(ew, k1);
        unsigned p2 = __shfl(ew, k2);
        unsigned p3 = __shfl(ew, k3);
        if (k0 < nfull) gacc(acc, p0, j, srcMirror);
        if (k1 < nfull) gacc(acc, p1, j, srcMirror);
        if (k2 < nfull) gacc(acc, p2, j, srcMirror);
        if (k3 < nfull) gacc(acc, p3, j, srcMirror);
    }
    for (int e = beg + 64 + g; e < end; e += 4) {
        unsigned p = s_edges[e];
        gacc(acc, p, j, srcMirror);
    }
    acc.x += __shfl_xor(acc.x, 16); acc.y += __shfl_xor(acc.y, 16);
    acc.z += __shfl_xor(acc.z, 16); acc.w += __shfl_xor(acc.w, 16);
    acc.x += __shfl_xor(acc.x, 32); acc.y += __shfl_xor(acc.y, 32);
    acc.z += __shfl_xor(acc.z, 32); acc.w += __shfl_xor(acc.w, 32);
    return acc;
}

__global__ void __launch_bounds__(256) spmm_gather_bf16_mid(const int* __restrict__ row_ptr,
                                                            const unsigned* __restrict__ s_edges,
                                                            const unsigned short* __restrict__ srcMirror,
                                                            float* __restrict__ dstStacked,
                                                            unsigned short* __restrict__ dstMirror) {
    int wave = (blockIdx.x * blockDim.x + threadIdx.x) >> 6;
    if (wave >= N_NODES) return;
    int lane = threadIdx.x & 63;
    int g = lane >> 4, j = lane & 15;
    float4 acc = spmm_row_core(row_ptr[wave], row_ptr[wave + 1], g, j, lane, s_edges, srcMirror);
    if (lane < 16) {
        *(float4*)(dstStacked + (size_t)wave * 256 + j * 4) = acc;
        ushort4 o;
        o.x = f32_to_bf16_rtn(acc.x); o.y = f32_to_bf16_rtn(acc.y);
        o.z = f32_to_bf16_rtn(acc.z); o.w = f32_to_bf16_rtn(acc.w);
        *(ushort4*)(dstMirror + (size_t)wave * 64 + j * 4) = o;
    }
}

// Last layer: fuse the 4-layer mean + layer-0 copy into the same dispatch.
__global__ void __launch_bounds__(256) spmm_gather_bf16_last(const int* __restrict__ row_ptr,
                                                             const unsigned* __restrict__ s_edges,
                                                             const unsigned short* __restrict__ srcMirror,
                                                             const float* __restrict__ emb,
                                                             float* __restrict__ stacked,
                                                             float* __restrict__ meanOut) {
    int wave = (blockIdx.x * blockDim.x + threadIdx.x) >> 6;
    if (wave >= N_NODES) return;
    int lane = threadIdx.x & 63;
    int g = lane >> 4, j = lane & 15;
    float4 acc = spmm_row_core(row_ptr[wave], row_ptr[wave + 1], g, j, lane, s_edges, srcMirror);
    if (lane < 16) {
        float4* base = (float4*)stacked + (size_t)wave * 64;
        float4 a = ((const float4*)emb)[wave * 16 + j];
        float4 b = base[16 + j];
        float4 c = base[32 + j];
        base[j] = a;          // layer 0
        base[48 + j] = acc;   // layer 3
        float4 s;
        s.x = 0.25f * (a.x + b.x + c.x + acc.x);
        s.y = 0.25f * (a.y + b.y + c.y + acc.y);
        s.z = 0.25f * (a.z + b.z + c.z + acc.z);
        s.w = 0.25f * (a.w + b.w + c.w + acc.w);
        ((float4*)meanOut)[wave * 16 + j] = s;
    }
}

// ---------- mean over 4 layers (f32 fallback path) ----------
__global__ void mean_layers(const float* __restrict__ emb,
                            float* __restrict__ stacked,
                            float* __restrict__ meanOut) {
    int t = blockIdx.x * blockDim.x + threadIdx.x;   // [0, N_NODES*16)
    if (t >= N_NODES * 16) return;
    int n = t >> 4;
    int j = t & 15;
    float4* base = (float4*)stacked + (size_t)n * 64;
    float4 a = ((const float4*)emb)[t];
    float4 b = base[16 + j];
    float4 c = base[32 + j];
    float4 d = base[48 + j];
    base[j] = a;
    float4 s;
    s.x = 0.25f * (a.x + b.x + c.x + d.x);
    s.y = 0.25f * (a.y + b.y + c.y + d.y);
    s.z = 0.25f * (a.z + b.z + c.z + d.z);
    s.w = 0.25f * (a.w + b.w + c.w + d.w);
    ((float4*)meanOut)[t] = s;
}

// ---------- mid fallback: fp32 CSR gather ----------

__global__ void scatter_edges_int2(const int* __restrict__ rows, const int* __restrict__ cols,
                                   const float* __restrict__ vals,
                                   const int* __restrict__ row_ptr, int* __restrict__ fill,
                                   int2* __restrict__ s_colval) {
    int e = blockIdx.x * blockDim.x + threadIdx.x;
    if (e >= N_EDGES) return;
    int r = rows[e];
    int pos = row_ptr[r] + atomicAdd(&fill[r], 1);
    int2 p; p.x = cols[e]; p.y = __float_as_int(vals[e]);
    s_colval[pos] = p;
}

__global__ void __launch_bounds__(256) spmm_gather_f32(const int* __restrict__ row_ptr,
                                                       const int2* __restrict__ s_colval,
                                                       const float* __restrict__ src, int srcStride,
                                                       float* __restrict__ dst) {
    int wave = (blockIdx.x * blockDim.x + threadIdx.x) >> 6;
    if (wave >= N_NODES) return;
    int lane = threadIdx.x & 63;
    int g = lane >> 4, j = lane & 15;
    int beg = row_ptr[wave], end = row_ptr[wave + 1];
    float4 acc = make_float4(0.f, 0.f, 0.f, 0.f);
    int e = beg + g;
    for (; e + 4 < end; e += 8) {
        int2 p0 = s_colval[e], p1 = s_colval[e + 4];
        float v0 = __int_as_float(p0.y), v1 = __int_as_float(p1.y);
        float4 m0 = *(const float4*)(src + (size_t)p0.x * srcStride + j * 4);
        float4 m1 = *(const float4*)(src + (size_t)p1.x * srcStride + j * 4);
        acc.x += v0 * m0.x + v1 * m1.x; acc.y += v0 * m0.y + v1 * m1.y;
        acc.z += v0 * m0.z + v1 * m1.z; acc.w += v0 * m0.w + v1 * m1.w;
    }
    for (; e < end; e += 4) {
        int2 p = s_colval[e];
        float v = __int_as_float(p.y);
        float4 m = *(const float4*)(src + (size_t)p.x * srcStride + j * 4);
        acc.x += v * m.x; acc.y += v * m.y; acc.z += v * m.z; acc.w += v * m.w;
    }
    acc.x += __shfl_xor(acc.x, 16); acc.y += __shfl_xor(acc.y, 16);
    acc.z += __shfl_xor(acc.z, 16); acc.w += __shfl_xor(acc.w, 16);
    acc.x += __shfl_xor(acc.x, 32); acc.y += __shfl_xor(acc.y, 32);
    acc.z += __shfl_xor(acc.z, 32); acc.w += __shfl_xor(acc.w, 32);
    if (lane < 16)
        *(float4*)(dst + (size_t)wave * 256 + j * 4) = acc;
}

// ---------- last fallback: atomic scatter ----------

__global__ void init_stacked_full(const float* __restrict__ emb, float* __restrict__ stacked) {
    int t = blockIdx.x * blockDim.x + threadIdx.x;
    if (t >= N_NODES * 64) return;
    int n = t >> 6, j = t & 63;
    float4 v = (j < 16) ? ((const float4*)emb)[n * 16 + j] : make_float4(0.f, 0.f, 0.f, 0.f);
    ((float4*)stacked)[n * 64 + j] = v;
}

__global__ void spmm_atomic(const int* __restrict__ rows, const int* __restrict__ cols,
                            const float* __restrict__ vals, float* __restrict__ stacked,
                            int lprev) {
    int t = blockIdx.x * blockDim.x + threadIdx.x;
    int e = t >> 4, j = t & 15;
    if (e >= N_EDGES) return;
    int r = rows[e], c = cols[e];
    float v = vals[e];
    const float4* src = (const float4*)(stacked + (size_t)c * 256 + lprev * 64);
    float4 m = src[j];
    float* dst = stacked + (size_t)r * 256 + (lprev + 1) * 64 + j * 4;
    atomicAdd(dst + 0, v * m.x); atomicAdd(dst + 1, v * m.y);
    atomicAdd(dst + 2, v * m.z); atomicAdd(dst + 3, v * m.w);
}

__global__ void mean_layers_plain(const float* __restrict__ stacked, float* __restrict__ meanOut) {
    int t = blockIdx.x * blockDim.x + threadIdx.x;
    if (t >= N_NODES * 16) return;
    int n = t >> 4, j = t & 15;
    const float4* base = (const float4*)(stacked + (size_t)n * 256);
    float4 a = base[j], b = base[16 + j], c = base[32 + j], d = base[48 + j];
    float4 s;
    s.x = 0.25f * (a.x + b.x + c.x + d.x);
    s.y = 0.25f * (a.y + b.y + c.y + d.y);
    s.z = 0.25f * (a.z + b.z + c.z + d.z);
    s.w = 0.25f * (a.w + b.w + c.w + d.w);
    ((float4*)meanOut)[t] = s;
}

extern "C" void kernel_launch(void* const* d_in, const int* in_sizes, int n_in,
                              void* d_out, int out_size, void* d_ws, size_t ws_size,
                              hipStream_t stream) {
    const float* emb  = (const float*)d_in[0];
    const int*   rows = (const int*)d_in[1];
    const int*   cols = (const int*)d_in[2];
    const float* vals = (const float*)d_in[3];

    float* meanOut = (float*)d_out;
    float* stacked = (float*)d_out + (size_t)N_NODES * EMB_DIM;

    const size_t headInts = (size_t)(N_NODES * 2 + 1 + 2 * N_SCAN_BLOCKS);
    size_t need_bf16 = headInts * sizeof(int) + 64
                     + (size_t)N_EDGES * sizeof(unsigned)
                     + 2 * (size_t)N_NODES * EMB_DIM * sizeof(unsigned short);
    size_t need_f32  = headInts * sizeof(int) + 64 + (size_t)N_EDGES * sizeof(int2);

    if (ws_size >= need_bf16) {
        char* w = (char*)d_ws;
        int* counts    = (int*)w;  w += (size_t)N_NODES * sizeof(int);
        int* row_ptr   = (int*)w;  w += (size_t)(N_NODES + 1) * sizeof(int);
        int* blockSums = (int*)w;  w += (size_t)N_SCAN_BLOCKS * sizeof(int);
        int* blockOffs = (int*)w;  w += (size_t)N_SCAN_BLOCKS * sizeof(int);
        w = (char*)(((uintptr_t)w + 15) & ~(uintptr_t)15);
        unsigned* s_edges = (unsigned*)w;  w += (size_t)N_EDGES * sizeof(unsigned);
        unsigned short* mirrorA = (unsigned short*)w;  w += (size_t)N_NODES * EMB_DIM * sizeof(unsigned short);
        unsigned short* mirrorB = (unsigned short*)w;
        // Phase-A record staging aliases mirrorA+mirrorB (3.2M * 8B = 25.6 MB,
        // exactly the two mirrors). Mirrors are written only AFTER the build.
        uint2* records = (uint2*)mirrorA;

        hipMemsetAsync(counts, 0, (size_t)N_NODES * sizeof(int), stream);
        {
            int block = 256, grid = (N_EDGES + block - 1) / block;
            count_rows<<<grid, block, 0, stream>>>(rows, counts);
        }
        scan_phase1<<<N_SCAN_BLOCKS, SCAN_BLOCK, 0, stream>>>(counts, blockSums);
        scan_phase2<<<1, 256, 0, stream>>>(blockSums, blockOffs, row_ptr);
        scan_phase3<<<N_SCAN_BLOCKS, SCAN_BLOCK, 0, stream>>>(counts, blockOffs, row_ptr);
        // counts array is free now -> reuse as bucketFill (NBINS ints).
        int* bucketFill = counts;
        hipMemsetAsync(bucketFill, 0, (size_t)NBINS * sizeof(int), stream);
        build_sortA<<<NCHUNKS, 256, 0, stream>>>(rows, cols, vals, row_ptr, bucketFill, records);
        build_phaseB<<<NBINS, 256, 0, stream>>>(row_ptr, records, s_edges);
        {
            int total = N_NODES * 16;
            int block = 256, grid = (total + block - 1) / block;
            emb_to_bf16<<<grid, block, 0, stream>>>(emb, (ushort4*)mirrorA);
        }
        {
            long long threads = (long long)N_NODES * 64;
            int block = 256;
            int grid = (int)((threads + block - 1) / block);
            spmm_gather_bf16_mid<<<grid, block, 0, stream>>>(row_ptr, s_edges, mirrorA, stacked + 1 * 64, mirrorB);
            spmm_gather_bf16_mid<<<grid, block, 0, stream>>>(row_ptr, s_edges, mirrorB, stacked + 2 * 64, mirrorA);
            spmm_gather_bf16_last<<<grid, block, 0, stream>>>(row_ptr, s_edges, mirrorA, emb, stacked, meanOut);
        }
    } else if (ws_size >= need_f32) {
        char* w = (char*)d_ws;
        int* counts    = (int*)w;  w += (size_t)N_NODES * sizeof(int);
        int* row_ptr   = (int*)w;  w += (size_t)(N_NODES + 1) * sizeof(int);
        int* blockSums = (int*)w;  w += (size_t)N_SCAN_BLOCKS * sizeof(int);
        int* blockOffs = (int*)w;  w += (size_t)N_SCAN_BLOCKS * sizeof(int);
        w = (char*)(((uintptr_t)w + 15) & ~(uintptr_t)15);
        int2* s_colval = (int2*)w;

        hipMemsetAsync(counts, 0, (size_t)N_NODES * sizeof(int), stream);
        {
            int block = 256, grid = (N_EDGES + block - 1) / block;
            count_rows<<<grid, block, 0, stream>>>(rows, counts);
        }
        scan_phase1<<<N_SCAN_BLOCKS, SCAN_BLOCK, 0, stream>>>(counts, blockSums);
        scan_phase2<<<1, 256, 0, stream>>>(blockSums, blockOffs, row_ptr);
        scan_phase3<<<N_SCAN_BLOCKS, SCAN_BLOCK, 0, stream>>>(counts, blockOffs, row_ptr);
        hipMemsetAsync(counts, 0, (size_t)N_NODES * sizeof(int), stream);
        {
            int block = 256, grid = (N_EDGES + block - 1) / block;
            scatter_edges_int2<<<grid, block, 0, stream>>>(rows, cols, vals, row_ptr, counts, s_colval);
        }
        {
            long long threads = (long long)N_NODES * 64;
            int block = 256;
            int grid = (int)((threads + block - 1) / block);
            spmm_gather_f32<<<grid, block, 0, stream>>>(row_ptr, s_colval, emb, 64, stacked + 1 * 64);
            spmm_gather_f32<<<grid, block, 0, stream>>>(row_ptr, s_colval, stacked + 1 * 64, 256, stacked + 2 * 64);
            spmm_gather_f32<<<grid, block, 0, stream>>>(row_ptr, s_colval, stacked + 2 * 64, 256, stacked + 3 * 64);
        }
        {
            int total = N_NODES * 16;
            int block = 256, grid = (total + block - 1) / block;
            mean_layers<<<grid, block, 0, stream>>>(emb, stacked, meanOut);
        }
    } else {
        {
            int total = N_NODES * 64;
            int block = 256, grid = (total + block - 1) / block;
            init_stacked_full<<<grid, block, 0, stream>>>(emb, stacked);
        }
        {
            long long total = (long long)N_EDGES * 16;
            int block = 256, grid = (int)((total + block - 1) / block);
            for (int l = 0; l < N_LAYERS; ++l)
                spmm_atomic<<<grid, block, 0, stream>>>(rows, cols, vals, stacked, l);
        }
        {
            int total = N_NODES * 16;
            int block = 256, grid = (total + block - 1) / block;
            mean_layers_plain<<<grid, block, 0, stream>>>(stacked, meanOut);
        }
    }
}

// Round 6
// 572.592 us; speedup vs baseline: 1.4017x; 1.1352x over previous
//
#include <hip/hip_runtime.h>
#include <hip/hip_fp16.h>

#define N_NODES 100000
#define EMB_DIM 64
#define N_EDGES 3200000
#define N_LAYERS 3

#define SCAN_BLOCK 512
#define N_SCAN_BLOCKS ((N_NODES + SCAN_BLOCK - 1) / SCAN_BLOCK)   // 196

// Coarse bins for the two-phase CSR build.
#define ABINROWS 256
#define NBINS ((N_NODES + ABINROWS - 1) / ABINROWS)   // 391
#define NBINS_P 512
#define ACHUNK 2048
#define AEPT 8
#define NCHUNKS ((N_EDGES + ACHUNK - 1) / ACHUNK)     // 1563
#define BCHUNK 4096
#define NBCHUNKS ((N_EDGES + BCHUNK - 1) / BCHUNK)    // 782

// d_out layout: mean [N_NODES*64] first, then stacked [N_NODES*4*64]
// stacked[n][l][d] at n*256 + l*64 + d

__device__ __forceinline__ unsigned short f32_to_bf16_rtn(float f) {
    unsigned u = __float_as_uint(f);
    unsigned r = u + 0x7FFFu + ((u >> 16) & 1u);
    return (unsigned short)(r >> 16);
}
__device__ __forceinline__ float bf16_to_f32(unsigned short h) {
    return __uint_as_float(((unsigned)h) << 16);
}

// ---------- bin-level counting (replaces per-row count_rows + 3 scan kernels) ----------
// LDS-private histogram per WG -> <=391 global atomics per WG. Kills the
// 100 MB atomic-writeback traffic count_rows had (R5 counters).

__global__ void __launch_bounds__(256) bin_count(const int* __restrict__ rows,
                                                 int* __restrict__ binCounts) {
    __shared__ int h[NBINS];
    int t = threadIdx.x;
    for (int i = t; i < NBINS; i += 256) h[i] = 0;
    __syncthreads();
    int base = blockIdx.x * BCHUNK;
    int n = N_EDGES - base; if (n > BCHUNK) n = BCHUNK;
    for (int i = t; i < n; i += 256) atomicAdd(&h[rows[base + i] >> 8], 1);
    __syncthreads();
    for (int i = t; i < NBINS; i += 256) {
        int c = h[i];
        if (c) atomicAdd(&binCounts[i], c);
    }
}

__global__ void __launch_bounds__(512) bin_scan(const int* __restrict__ binCounts,
                                                int* __restrict__ binPtr) {
    __shared__ int sm[512];
    int t = threadIdx.x;
    int v = (t < NBINS) ? binCounts[t] : 0;
    sm[t] = v;
    __syncthreads();
    for (int off = 1; off < 512; off <<= 1) {
        int u = (t >= off) ? sm[t - off] : 0;
        __syncthreads();
        sm[t] += u;
        __syncthreads();
    }
    if (t < NBINS) binPtr[t + 1] = sm[t];
    if (t == 0) binPtr[0] = 0;
}

// ---------- legacy per-row count + scan (f32 fallback path only) ----------

__global__ void count_rows(const int* __restrict__ rows, int* __restrict__ counts) {
    int e = blockIdx.x * blockDim.x + threadIdx.x;
    if (e >= N_EDGES) return;
    atomicAdd(&counts[rows[e]], 1);
}

__global__ void __launch_bounds__(SCAN_BLOCK) scan_phase1(const int* __restrict__ counts,
                                                          int* __restrict__ blockSums) {
    __shared__ int sm[SCAN_BLOCK];
    int idx = blockIdx.x * SCAN_BLOCK + threadIdx.x;
    int v = (idx < N_NODES) ? counts[idx] : 0;
    sm[threadIdx.x] = v;
    __syncthreads();
    for (int off = SCAN_BLOCK / 2; off > 0; off >>= 1) {
        if (threadIdx.x < off) sm[threadIdx.x] += sm[threadIdx.x + off];
        __syncthreads();
    }
    if (threadIdx.x == 0) blockSums[blockIdx.x] = sm[0];
}

__global__ void __launch_bounds__(256) scan_phase2(const int* __restrict__ blockSums,
                                                   int* __restrict__ blockOffs,
                                                   int* __restrict__ row_ptr) {
    __shared__ int sm[256];
    int t = threadIdx.x;
    int v = (t < N_SCAN_BLOCKS) ? blockSums[t] : 0;
    sm[t] = v;
    __syncthreads();
    for (int off = 1; off < 256; off <<= 1) {
        int u = (t >= off) ? sm[t - off] : 0;
        __syncthreads();
        sm[t] += u;
        __syncthreads();
    }
    if (t < N_SCAN_BLOCKS) blockOffs[t] = (t == 0) ? 0 : sm[t - 1];
    if (t == 255) row_ptr[N_NODES] = sm[255];
}

__global__ void __launch_bounds__(SCAN_BLOCK) scan_phase3(const int* __restrict__ counts,
                                                          const int* __restrict__ blockOffs,
                                                          int* __restrict__ row_ptr) {
    __shared__ int sm[SCAN_BLOCK];
    int idx = blockIdx.x * SCAN_BLOCK + threadIdx.x;
    int t = threadIdx.x;
    int v = (idx < N_NODES) ? counts[idx] : 0;
    sm[t] = v;
    __syncthreads();
    for (int off = 1; off < SCAN_BLOCK; off <<= 1) {
        int u = (t >= off) ? sm[t - off] : 0;
        __syncthreads();
        sm[t] += u;
        __syncthreads();
    }
    if (idx < N_NODES) row_ptr[idx] = blockOffs[blockIdx.x] + sm[t] - v;
}

// ---------- phase A: LDS counting-sort partition (dense run writes) ----------
// Packed edge: col (17 bits) << 15 | fp16(val) low 15 bits (val>=0 so sign=0).

__global__ void __launch_bounds__(256) build_sortA(const int* __restrict__ rows,
                                                   const int* __restrict__ cols,
                                                   const float* __restrict__ vals,
                                                   const int* __restrict__ binPtr,
                                                   int* __restrict__ bucketFill,
                                                   uint2* __restrict__ records) {
    __shared__ int binCnt[NBINS_P];
    __shared__ int binInc[NBINS_P];   // inclusive prefix of binCnt
    __shared__ int binCur[NBINS_P];
    __shared__ int binG[NBINS];       // global dst base of this WG's run per bin
    __shared__ uint2 buf[ACHUNK];     // bin-sorted records

    int base = blockIdx.x * ACHUNK;
    int n = N_EDGES - base; if (n > ACHUNK) n = ACHUNK;
    int t = threadIdx.x;

    for (int i = t; i < NBINS_P; i += 256) { binCnt[i] = 0; binCur[i] = 0; }
    __syncthreads();

    // Load AEPT edges/thread (static unroll -> registers) + histogram.
    int r_[AEPT]; unsigned pk_[AEPT];
#pragma unroll AEPT
    for (int k = 0; k < AEPT; ++k) {
        int i = t + k * 256;
        r_[k] = 0; pk_[k] = 0;
        if (i < n) {
            int e = base + i;
            int r = rows[e];
            unsigned hb = __half_as_ushort(__float2half(vals[e]));
            r_[k] = r;
            pk_[k] = (((unsigned)cols[e]) << 15) | (hb & 0x7FFFu);
            atomicAdd(&binCnt[r >> 8], 1);
        }
    }
    __syncthreads();

    // Hillis-Steele inclusive scan over NBINS_P entries (2 per thread).
    binInc[t] = binCnt[t];
    binInc[t + 256] = binCnt[t + 256];
    __syncthreads();
    for (int off = 1; off < NBINS_P; off <<= 1) {
        int i0 = t, i1 = t + 256;
        int v0 = (i0 >= off) ? binInc[i0 - off] : 0;
        int v1 = (i1 >= off) ? binInc[i1 - off] : 0;
        __syncthreads();
        binInc[i0] += v0;
        binInc[i1] += v1;
        __syncthreads();
    }

    // Scatter records into LDS at bin-sorted positions.
#pragma unroll AEPT
    for (int k = 0; k < AEPT; ++k) {
        int i = t + k * 256;
        if (i < n) {
            int b = r_[k] >> 8;
            int slot = (binInc[b] - binCnt[b]) + atomicAdd(&binCur[b], 1);
            buf[slot] = make_uint2((unsigned)r_[k], pk_[k]);
        }
    }
    // One global reservation per non-empty bin.
    for (int b = t; b < NBINS; b += 256) {
        int c = binCnt[b];
        if (c > 0) binG[b] = binPtr[b] + atomicAdd(&bucketFill[b], c);
    }
    __syncthreads();

    // Coalesced copy-out: consecutive p within a run -> consecutive global dst.
    for (int p = t; p < n; p += 256) {
        uint2 rec = buf[p];
        int b = (int)(rec.x >> 8);
        int dst = binG[b] + (p - (binInc[b] - binCnt[b]));
        records[dst] = rec;
    }
}

// ---------- phase B: per-bin row_ptr derivation + scatter to exact CSR slots ----------
// Streams the bin's records twice (2nd pass is L2-hit): pass 1 builds the
// per-row histogram in LDS + scans it + writes row_ptr densely; pass 2
// scatters edge words into the bin's contiguous s_edges window.
__global__ void __launch_bounds__(256) build_phaseB(const int* __restrict__ binPtr,
                                                    const uint2* __restrict__ records,
                                                    unsigned* __restrict__ s_edges,
                                                    int* __restrict__ row_ptr) {
    __shared__ int lcnt[ABINROWS];
    __shared__ int linc[ABINROWS];
    __shared__ int lrp[ABINROWS];
    __shared__ int lfill[ABINROWS];
    int b = blockIdx.x;
    int t = threadIdx.x;
    int r0 = b * ABINROWS;
    int r1 = r0 + ABINROWS; if (r1 > N_NODES) r1 = N_NODES;
    int nr = r1 - r0;
    int beg = binPtr[b];
    int end = binPtr[b + 1];

    lcnt[t] = 0; lfill[t] = 0;
    __syncthreads();
    // Pass 1: per-row histogram.
    for (int i = beg + t; i < end; i += 256) {
        atomicAdd(&lcnt[(int)records[i].x - r0], 1);
    }
    __syncthreads();
    // Inclusive scan of 256 entries.
    linc[t] = lcnt[t];
    __syncthreads();
    for (int off = 1; off < 256; off <<= 1) {
        int u = (t >= off) ? linc[t - off] : 0;
        __syncthreads();
        linc[t] += u;
        __syncthreads();
    }
    lrp[t] = beg + linc[t] - lcnt[t];   // exclusive prefix + bin base
    // Dense row_ptr write; right boundary (t==nr position) equals next bin's
    // base -> duplicate same-value write at bin seams, benign.
    if (t < nr) row_ptr[r0 + t] = lrp[t];
    if (t == 0) row_ptr[r0 + nr] = end;
    __syncthreads();
    // Pass 2: scatter (records re-read is L2-resident).
    for (int i = beg + t; i < end; i += 256) {
        uint2 rec = records[i];
        int lr = (int)rec.x - r0;
        int lp = atomicAdd(&lfill[lr], 1);
        s_edges[lrp[lr] + lp] = rec.y;
    }
}

// ---------- emb -> bf16 mirror ----------
__global__ void emb_to_bf16(const float* __restrict__ emb, ushort4* __restrict__ mirror) {
    int t = blockIdx.x * blockDim.x + threadIdx.x;   // [0, N_NODES*16)
    if (t >= N_NODES * 16) return;
    float4 v = ((const float4*)emb)[t];
    ushort4 o;
    o.x = f32_to_bf16_rtn(v.x); o.y = f32_to_bf16_rtn(v.y);
    o.z = f32_to_bf16_rtn(v.z); o.w = f32_to_bf16_rtn(v.w);
    mirror[t] = o;
}

// ---------- SpMM gather core, bf16 source: one wave per destination node ----------
// 4 groups x 16 lanes; lane j of a group owns bf16x4 chunk j of the 64-dim row.
// Edge words staged via ONE coalesced per-lane load, distributed with __shfl.
// Control flow is wave-uniform (shfl from inactive lanes is undefined on CDNA).

__device__ __forceinline__ void gacc(float4& acc, unsigned p, int j,
                                     const unsigned short* __restrict__ srcMirror) {
    float v = __half2float(__ushort_as_half((unsigned short)(p & 0x7FFFu)));
    ushort4 m = *(const ushort4*)(srcMirror + (size_t)(p >> 15) * 64 + j * 4);
    acc.x += v * bf16_to_f32(m.x);
    acc.y += v * bf16_to_f32(m.y);
    acc.z += v * bf16_to_f32(m.z);
    acc.w += v * bf16_to_f32(m.w);
}

__device__ __forceinline__ float4 spmm_row_core(int beg, int end, int g, int j, int lane,
                                                const unsigned* __restrict__ s_edges,
                                                const unsigned short* __restrict__ srcMirror) {
    int deg = end - beg;                  // wave-uniform
    unsigned ew = (lane < deg) ? s_edges[beg + lane] : 0u;
    float4 acc = make_float4(0.f, 0.f, 0.f, 0.f);
    int nfull = deg < 64 ? deg : 64;      // wave-uniform
    for (int kb = 0; kb < nfull; kb += 16) {
        int k0 = kb + g, k1 = kb + g + 4, k2 = kb + g + 8, k3 = kb + g + 12;
        unsigned p0 = __shfl(ew, k0);
        unsigned p1 = __shfl(ew, k1);
        unsigned p2 = __shfl(ew, k2);
        unsigned p3 = __shfl(ew, k3);
        if (k0 < nfull) gacc(acc, p0, j, srcMirror);
        if (k1 < nfull) gacc(acc, p1, j, srcMirror);
        if (k2 < nfull) gacc(acc, p2, j, srcMirror);
        if (k3 < nfull) gacc(acc, p3, j, srcMirror);
    }
    for (int e = beg + 64 + g; e < end; e += 4) {
        unsigned p = s_edges[e];
        gacc(acc, p, j, srcMirror);
    }
    acc.x += __shfl_xor(acc.x, 16); acc.y += __shfl_xor(acc.y, 16);
    acc.z += __shfl_xor(acc.z, 16); acc.w += __shfl_xor(acc.w, 16);
    acc.x += __shfl_xor(acc.x, 32); acc.y += __shfl_xor(acc.y, 32);
    acc.z += __shfl_xor(acc.z, 32); acc.w += __shfl_xor(acc.w, 32);
    return acc;
}

__global__ void __launch_bounds__(256) spmm_gather_bf16_mid(const int* __restrict__ row_ptr,
                                                            const unsigned* __restrict__ s_edges,
                                                            const unsigned short* __restrict__ srcMirror,
                                                            float* __restrict__ dstStacked,
                                                            unsigned short* __restrict__ dstMirror) {
    int wave = (blockIdx.x * blockDim.x + threadIdx.x) >> 6;
    if (wave >= N_NODES) return;
    int lane = threadIdx.x & 63;
    int g = lane >> 4, j = lane & 15;
    float4 acc = spmm_row_core(row_ptr[wave], row_ptr[wave + 1], g, j, lane, s_edges, srcMirror);
    if (lane < 16) {
        *(float4*)(dstStacked + (size_t)wave * 256 + j * 4) = acc;
        ushort4 o;
        o.x = f32_to_bf16_rtn(acc.x); o.y = f32_to_bf16_rtn(acc.y);
        o.z = f32_to_bf16_rtn(acc.z); o.w = f32_to_bf16_rtn(acc.w);
        *(ushort4*)(dstMirror + (size_t)wave * 64 + j * 4) = o;
    }
}

// Last layer: fuse the 4-layer mean + layer-0 copy into the same dispatch.
__global__ void __launch_bounds__(256) spmm_gather_bf16_last(const int* __restrict__ row_ptr,
                                                             const unsigned* __restrict__ s_edges,
                                                             const unsigned short* __restrict__ srcMirror,
                                                             const float* __restrict__ emb,
                                                             float* __restrict__ stacked,
                                                             float* __restrict__ meanOut) {
    int wave = (blockIdx.x * blockDim.x + threadIdx.x) >> 6;
    if (wave >= N_NODES) return;
    int lane = threadIdx.x & 63;
    int g = lane >> 4, j = lane & 15;
    float4 acc = spmm_row_core(row_ptr[wave], row_ptr[wave + 1], g, j, lane, s_edges, srcMirror);
    if (lane < 16) {
        float4* base = (float4*)stacked + (size_t)wave * 64;
        float4 a = ((const float4*)emb)[wave * 16 + j];
        float4 b = base[16 + j];
        float4 c = base[32 + j];
        base[j] = a;          // layer 0
        base[48 + j] = acc;   // layer 3
        float4 s;
        s.x = 0.25f * (a.x + b.x + c.x + acc.x);
        s.y = 0.25f * (a.y + b.y + c.y + acc.y);
        s.z = 0.25f * (a.z + b.z + c.z + acc.z);
        s.w = 0.25f * (a.w + b.w + c.w + acc.w);
        ((float4*)meanOut)[wave * 16 + j] = s;
    }
}

// ---------- mean over 4 layers (f32 fallback path) ----------
__global__ void mean_layers(const float* __restrict__ emb,
                            float* __restrict__ stacked,
                            float* __restrict__ meanOut) {
    int t = blockIdx.x * blockDim.x + threadIdx.x;   // [0, N_NODES*16)
    if (t >= N_NODES * 16) return;
    int n = t >> 4;
    int j = t & 15;
    float4* base = (float4*)stacked + (size_t)n * 64;
    float4 a = ((const float4*)emb)[t];
    float4 b = base[16 + j];
    float4 c = base[32 + j];
    float4 d = base[48 + j];
    base[j] = a;
    float4 s;
    s.x = 0.25f * (a.x + b.x + c.x + d.x);
    s.y = 0.25f * (a.y + b.y + c.y + d.y);
    s.z = 0.25f * (a.z + b.z + c.z + d.z);
    s.w = 0.25f * (a.w + b.w + c.w + d.w);
    ((float4*)meanOut)[t] = s;
}

// ---------- mid fallback: fp32 CSR gather ----------

__global__ void scatter_edges_int2(const int* __restrict__ rows, const int* __restrict__ cols,
                                   const float* __restrict__ vals,
                                   const int* __restrict__ row_ptr, int* __restrict__ fill,
                                   int2* __restrict__ s_colval) {
    int e = blockIdx.x * blockDim.x + threadIdx.x;
    if (e >= N_EDGES) return;
    int r = rows[e];
    int pos = row_ptr[r] + atomicAdd(&fill[r], 1);
    int2 p; p.x = cols[e]; p.y = __float_as_int(vals[e]);
    s_colval[pos] = p;
}

__global__ void __launch_bounds__(256) spmm_gather_f32(const int* __restrict__ row_ptr,
                                                       const int2* __restrict__ s_colval,
                                                       const float* __restrict__ src, int srcStride,
                                                       float* __restrict__ dst) {
    int wave = (blockIdx.x * blockDim.x + threadIdx.x) >> 6;
    if (wave >= N_NODES) return;
    int lane = threadIdx.x & 63;
    int g = lane >> 4, j = lane & 15;
    int beg = row_ptr[wave], end = row_ptr[wave + 1];
    float4 acc = make_float4(0.f, 0.f, 0.f, 0.f);
    int e = beg + g;
    for (; e + 4 < end; e += 8) {
        int2 p0 = s_colval[e], p1 = s_colval[e + 4];
        float v0 = __int_as_float(p0.y), v1 = __int_as_float(p1.y);
        float4 m0 = *(const float4*)(src + (size_t)p0.x * srcStride + j * 4);
        float4 m1 = *(const float4*)(src + (size_t)p1.x * srcStride + j * 4);
        acc.x += v0 * m0.x + v1 * m1.x; acc.y += v0 * m0.y + v1 * m1.y;
        acc.z += v0 * m0.z + v1 * m1.z; acc.w += v0 * m0.w + v1 * m1.w;
    }
    for (; e < end; e += 4) {
        int2 p = s_colval[e];
        float v = __int_as_float(p.y);
        float4 m = *(const float4*)(src + (size_t)p.x * srcStride + j * 4);
        acc.x += v * m.x; acc.y += v * m.y; acc.z += v * m.z; acc.w += v * m.w;
    }
    acc.x += __shfl_xor(acc.x, 16); acc.y += __shfl_xor(acc.y, 16);
    acc.z += __shfl_xor(acc.z, 16); acc.w += __shfl_xor(acc.w, 16);
    acc.x += __shfl_xor(acc.x, 32); acc.y += __shfl_xor(acc.y, 32);
    acc.z += __shfl_xor(acc.z, 32); acc.w += __shfl_xor(acc.w, 32);
    if (lane < 16)
        *(float4*)(dst + (size_t)wave * 256 + j * 4) = acc;
}

// ---------- last fallback: atomic scatter ----------

__global__ void init_stacked_full(const float* __restrict__ emb, float* __restrict__ stacked) {
    int t = blockIdx.x * blockDim.x + threadIdx.x;
    if (t >= N_NODES * 64) return;
    int n = t >> 6, j = t & 63;
    float4 v = (j < 16) ? ((const float4*)emb)[n * 16 + j] : make_float4(0.f, 0.f, 0.f, 0.f);
    ((float4*)stacked)[n * 64 + j] = v;
}

__global__ void spmm_atomic(const int* __restrict__ rows, const int* __restrict__ cols,
                            const float* __restrict__ vals, float* __restrict__ stacked,
                            int lprev) {
    int t = blockIdx.x * blockDim.x + threadIdx.x;
    int e = t >> 4, j = t & 15;
    if (e >= N_EDGES) return;
    int r = rows[e], c = cols[e];
    float v = vals[e];
    const float4* src = (const float4*)(stacked + (size_t)c * 256 + lprev * 64);
    float4 m = src[j];
    float* dst = stacked + (size_t)r * 256 + (lprev + 1) * 64 + j * 4;
    atomicAdd(dst + 0, v * m.x); atomicAdd(dst + 1, v * m.y);
    atomicAdd(dst + 2, v * m.z); atomicAdd(dst + 3, v * m.w);
}

__global__ void mean_layers_plain(const float* __restrict__ stacked, float* __restrict__ meanOut) {
    int t = blockIdx.x * blockDim.x + threadIdx.x;
    if (t >= N_NODES * 16) return;
    int n = t >> 4, j = t & 15;
    const float4* base = (const float4*)(stacked + (size_t)n * 256);
    float4 a = base[j], b = base[16 + j], c = base[32 + j], d = base[48 + j];
    float4 s;
    s.x = 0.25f * (a.x + b.x + c.x + d.x);
    s.y = 0.25f * (a.y + b.y + c.y + d.y);
    s.z = 0.25f * (a.z + b.z + c.z + d.z);
    s.w = 0.25f * (a.w + b.w + c.w + d.w);
    ((float4*)meanOut)[t] = s;
}

extern "C" void kernel_launch(void* const* d_in, const int* in_sizes, int n_in,
                              void* d_out, int out_size, void* d_ws, size_t ws_size,
                              hipStream_t stream) {
    const float* emb  = (const float*)d_in[0];
    const int*   rows = (const int*)d_in[1];
    const int*   cols = (const int*)d_in[2];
    const float* vals = (const float*)d_in[3];

    float* meanOut = (float*)d_out;
    float* stacked = (float*)d_out + (size_t)N_NODES * EMB_DIM;

    const size_t headInts = (size_t)(N_NODES * 2 + 1 + 2 * N_SCAN_BLOCKS);
    size_t need_bf16 = headInts * sizeof(int) + 64
                     + (size_t)N_EDGES * sizeof(unsigned)
                     + 2 * (size_t)N_NODES * EMB_DIM * sizeof(unsigned short);
    size_t need_f32  = headInts * sizeof(int) + 64 + (size_t)N_EDGES * sizeof(int2);

    if (ws_size >= need_bf16) {
        char* w = (char*)d_ws;
        int* counts    = (int*)w;  w += (size_t)N_NODES * sizeof(int);
        int* row_ptr   = (int*)w;  w += (size_t)(N_NODES + 1) * sizeof(int);
        int* blockSums = (int*)w;  w += (size_t)N_SCAN_BLOCKS * sizeof(int);
        int* blockOffs = (int*)w;  w += (size_t)N_SCAN_BLOCKS * sizeof(int);
        w = (char*)(((uintptr_t)w + 15) & ~(uintptr_t)15);
        unsigned* s_edges = (unsigned*)w;  w += (size_t)N_EDGES * sizeof(unsigned);
        unsigned short* mirrorA = (unsigned short*)w;  w += (size_t)N_NODES * EMB_DIM * sizeof(unsigned short);
        unsigned short* mirrorB = (unsigned short*)w;
        // Phase-A record staging aliases mirrorA+mirrorB (3.2M * 8B = 25.6 MB).
        // Mirrors are written only AFTER the build consumes records.
        uint2* records = (uint2*)mirrorA;
        // Bin-level arrays live in the (otherwise unused) counts region.
        int* binCounts  = counts;                 // NBINS
        int* bucketFill = counts + NBINS;         // NBINS
        int* binPtr     = counts + 2 * NBINS;     // NBINS+1

        hipMemsetAsync(counts, 0, (size_t)(2 * NBINS) * sizeof(int), stream);
        bin_count<<<NBCHUNKS, 256, 0, stream>>>(rows, binCounts);
        bin_scan<<<1, 512, 0, stream>>>(binCounts, binPtr);
        build_sortA<<<NCHUNKS, 256, 0, stream>>>(rows, cols, vals, binPtr, bucketFill, records);
        build_phaseB<<<NBINS, 256, 0, stream>>>(binPtr, records, s_edges, row_ptr);
        {
            int total = N_NODES * 16;
            int block = 256, grid = (total + block - 1) / block;
            emb_to_bf16<<<grid, block, 0, stream>>>(emb, (ushort4*)mirrorA);
        }
        {
            long long threads = (long long)N_NODES * 64;
            int block = 256;
            int grid = (int)((threads + block - 1) / block);
            spmm_gather_bf16_mid<<<grid, block, 0, stream>>>(row_ptr, s_edges, mirrorA, stacked + 1 * 64, mirrorB);
            spmm_gather_bf16_mid<<<grid, block, 0, stream>>>(row_ptr, s_edges, mirrorB, stacked + 2 * 64, mirrorA);
            spmm_gather_bf16_last<<<grid, block, 0, stream>>>(row_ptr, s_edges, mirrorA, emb, stacked, meanOut);
        }
    } else if (ws_size >= need_f32) {
        char* w = (char*)d_ws;
        int* counts    = (int*)w;  w += (size_t)N_NODES * sizeof(int);
        int* row_ptr   = (int*)w;  w += (size_t)(N_NODES + 1) * sizeof(int);
        int* blockSums = (int*)w;  w += (size_t)N_SCAN_BLOCKS * sizeof(int);
        int* blockOffs = (int*)w;  w += (size_t)N_SCAN_BLOCKS * sizeof(int);
        w = (char*)(((uintptr_t)w + 15) & ~(uintptr_t)15);
        int2* s_colval = (int2*)w;

        hipMemsetAsync(counts, 0, (size_t)N_NODES * sizeof(int), stream);
        {
            int block = 256, grid = (N_EDGES + block - 1) / block;
            count_rows<<<grid, block, 0, stream>>>(rows, counts);
        }
        scan_phase1<<<N_SCAN_BLOCKS, SCAN_BLOCK, 0, stream>>>(counts, blockSums);
        scan_phase2<<<1, 256, 0, stream>>>(blockSums, blockOffs, row_ptr);
        scan_phase3<<<N_SCAN_BLOCKS, SCAN_BLOCK, 0, stream>>>(counts, blockOffs, row_ptr);
        hipMemsetAsync(counts, 0, (size_t)N_NODES * sizeof(int), stream);
        {
            int block = 256, grid = (N_EDGES + block - 1) / block;
            scatter_edges_int2<<<grid, block, 0, stream>>>(rows, cols, vals, row_ptr, counts, s_colval);
        }
        {
            long long threads = (long long)N_NODES * 64;
            int block = 256;
            int grid = (int)((threads + block - 1) / block);
            spmm_gather_f32<<<grid, block, 0, stream>>>(row_ptr, s_colval, emb, 64, stacked + 1 * 64);
            spmm_gather_f32<<<grid, block, 0, stream>>>(row_ptr, s_colval, stacked + 1 * 64, 256, stacked + 2 * 64);
            spmm_gather_f32<<<grid, block, 0, stream>>>(row_ptr, s_colval, stacked + 2 * 64, 256, stacked + 3 * 64);
        }
        {
            int total = N_NODES * 16;
            int block = 256, grid = (total + block - 1) / block;
            mean_layers<<<grid, block, 0, stream>>>(emb, stacked, meanOut);
        }
    } else {
        {
            int total = N_NODES * 64;
            int block = 256, grid = (total + block - 1) / block;
            init_stacked_full<<<grid, block, 0, stream>>>(emb, stacked);
        }
        {
            long long total = (long long)N_EDGES * 16;
            int block = 256, grid = (int)((total + block - 1) / block);
            for (int l = 0; l < N_LAYERS; ++l)
                spmm_atomic<<<grid, block, 0, stream>>>(rows, cols, vals, stacked, l);
        }
        {
            int total = N_NODES * 16;
            int block = 256, grid = (total + block - 1) / block;
            mean_layers_plain<<<grid, block, 0, stream>>>(stacked, meanOut);
        }
    }
}